// Round 1
// 362.641 us; speedup vs baseline: 1.0084x; 1.0084x over previous
//
#include <hip/hip_runtime.h>
#include <stdint.h>

// ---------------------------------------------------------------------------
// GNNWithMoE: 2x GGNN(edge-embed + gather + GRU) -> soft MoE -> mean pool
// ALL float tensors fp32; ints int32; out fp32. GEMMs via bf16 MFMA.
//
// Round-9: k_gru/k_moe were latency-bound (MfmaUtil 1.5%, Occ 17%, 5.5% HBM):
//  * k_gru: 4 waves per 16-node tile, wave j owns output cols [16j,16j+16)
//    (row-blocks {j, j+4, j+8} of w_ih/w_hh). 4x waves, 4x shorter MFMA
//    chains, 6 accumulators instead of 24. __syncthreads() after fragment
//    loads makes the in-place layer-2 call (out==x) race-free.
//  * k_moe: wave e owns expert e (8 MFMAs); wave 0 also does the gate MFMA;
//    combine through padded LDS vsm[4][16][65] + block reduce.
// Sub-bucket cap 8, ~Poisson(2) load; overflow -> k_ovf fallback (any input).
// Workspace (16B-aligned):
//   m[N*64] f32 | h[N*64] f32 | bkt_src[N*64] i32 | bkt_ea[N*64] ushort4 |
//   cur[8*N] i32 | ovfcnt[4] | ovf[32768] | wbf[65792] bf16 | partial[B*PS*64]
// ---------------------------------------------------------------------------

#define SUBCAP 8
#define OVF_MAX 32768
#define PS 16   // pool splits per graph

typedef __bf16 bf16x8 __attribute__((ext_vector_type(8)));
typedef float floatx4 __attribute__((ext_vector_type(4)));
typedef unsigned short us8 __attribute__((ext_vector_type(8)));

__device__ __forceinline__ unsigned short f2bf(float f){
  union { float f; unsigned u; } c; c.f = f;
  unsigned r = c.u + 0x7FFFu + ((c.u >> 16) & 1u);
  return (unsigned short)(r >> 16);
}
__device__ __forceinline__ float bf2f(unsigned short u){
  union { unsigned u; float f; } c; c.u = ((unsigned)u) << 16; return c.f;
}
__device__ __forceinline__ float sigm(float x){ return 1.f/(1.f + __expf(-x)); }

// fused: weight fp32->bf16 conversion + zero cur/ovfcnt  (cur is 8*N)
__global__ void k_init(const float* __restrict__ s0, const float* __restrict__ s1,
                       const float* __restrict__ s2, const float* __restrict__ s3,
                       const float* __restrict__ s4, const float* __restrict__ s5,
                       unsigned short* __restrict__ dst,
                       int* __restrict__ cur, int* __restrict__ ovfcnt, int N8){
  int i = blockIdx.x*blockDim.x + threadIdx.x;
  if (i < N8) cur[i] = 0;
  if (i == 0){ ovfcnt[0] = 0; }
  if (i >= 65792) return;
  const float* s; int off;
  if      (i < 12288){ s = s0; off = i; }
  else if (i < 24576){ s = s1; off = i - 12288; }
  else if (i < 36864){ s = s2; off = i - 24576; }
  else if (i < 49152){ s = s3; off = i - 36864; }
  else if (i < 49408){ s = s4; off = i - 49152; }
  else               { s = s5; off = i - 49408; }
  dst[i] = f2bf(s[off]);
}

// one atomic per edge into an XCD-local sub-bucket (counter AND data lines
// owned by one XCD under round-robin block dispatch); ea payload stored bf16.
__global__ void k_bucket(const int* __restrict__ ei, const float* __restrict__ ea,
                         int* __restrict__ cur, int* __restrict__ bkt_src,
                         ushort4* __restrict__ bkt_ea,
                         int* __restrict__ ovfcnt, int* __restrict__ ovf,
                         int E, int N){
  int e = blockIdx.x*blockDim.x + threadIdx.x;
  if (e >= E) return;
  int sub = blockIdx.x & 7;          // ~XCD id under round-robin dispatch
  int s = ei[e];
  int d = ei[E + e];
  size_t sb = (size_t)sub*N + d;
  int pos = atomicAdd(&cur[sb], 1);
  if (pos < SUBCAP){
    float4 v = *(const float4*)(ea + (size_t)e*4);
    ushort4 p; p.x = f2bf(v.x); p.y = f2bf(v.y); p.z = f2bf(v.z); p.w = f2bf(v.w);
    bkt_src[sb*SUBCAP + pos] = s;
    bkt_ea [sb*SUBCAP + pos] = p;
  } else {
    int o = atomicAdd(ovfcnt, 1);
    if (o < OVF_MAX) ovf[o] = e;
  }
}

// one wave per node, lane=dim; lane d also owns bucket slot (sub=d>>3,k=d&7):
// m[n,d] = x[n,d] + (deg+1)*b_edge[d] + w_edge[d,:].sum_e(ea[e,:]) + sum_e x[src,d]
// (overflow edges' x/ea terms added later by k_ovf; their bias IS counted here)
__global__ void __launch_bounds__(256) k_gather(
    const int* __restrict__ cur, const int* __restrict__ bkt_src,
    const ushort4* __restrict__ bkt_ea,
    const float* __restrict__ xin,
    const float* __restrict__ w_edge, const float* __restrict__ b_edge,
    float* __restrict__ m, int N){
  int n = (int)(((long long)blockIdx.x*blockDim.x + threadIdx.x) >> 6);
  if (n >= N) return;
  int d = threadIdx.x & 63;
  int sub = d >> 3, k = d & 7;
  size_t sb = (size_t)sub*N + n;
  int myc = cur[sb];
  // degAll = sum of the 8 sub-counts (each lane group replicates its sub's count)
  int contrib = (k == 0) ? myc : 0;
#pragma unroll
  for (int off = 1; off < 64; off <<= 1) contrib += __shfl_xor(contrib, off);
  int degAll = contrib;

  bool valid = k < min(myc, SUBCAP);
  int src = 0;
  float esx = 0.f, esy = 0.f, esz = 0.f, esw = 0.f;
  if (valid){
    src = bkt_src[sb*SUBCAP + k];
    ushort4 p = bkt_ea[sb*SUBCAP + k];
    esx = bf2f(p.x); esy = bf2f(p.y); esz = bf2f(p.z); esw = bf2f(p.w);
  }

  float4 wv = *(const float4*)(w_edge + d*4);
  float acc = xin[(size_t)n*64 + d] + (float)(degAll + 1) * b_edge[d];

  // x-row gather: wave-uniform ballot mask, ctz lane-extract, 4 loads in flight
  unsigned long long mm = __ballot(valid);
  while (mm){
    int l0 = (int)__builtin_ctzll(mm); mm &= mm - 1;
    int s0 = __shfl(src, l0);
    float a0 = xin[(size_t)s0*64 + d];
    float a1 = 0.f, a2 = 0.f, a3 = 0.f;
    if (mm){
      int l1 = (int)__builtin_ctzll(mm); mm &= mm - 1;
      int s1 = __shfl(src, l1);
      a1 = xin[(size_t)s1*64 + d];
      if (mm){
        int l2 = (int)__builtin_ctzll(mm); mm &= mm - 1;
        int s2 = __shfl(src, l2);
        a2 = xin[(size_t)s2*64 + d];
        if (mm){
          int l3 = (int)__builtin_ctzll(mm); mm &= mm - 1;
          int s3 = __shfl(src, l3);
          a3 = xin[(size_t)s3*64 + d];
        }
      }
    }
    acc += (a0 + a1) + (a2 + a3);
  }

  // butterfly-sum ea over all 64 lanes (invalid lanes contribute 0)
#pragma unroll
  for (int off = 1; off < 64; off <<= 1){
    esx += __shfl_xor(esx, off);
    esy += __shfl_xor(esy, off);
    esz += __shfl_xor(esz, off);
    esw += __shfl_xor(esw, off);
  }
  acc += esx*wv.x + esy*wv.y + esz*wv.z + esw*wv.w;
  m[(size_t)n*64 + d] = acc;
}

// fallback for sub-bucket-overflow edges (~1e2 expected): atomic scatter, no bias
__global__ void k_ovf(const int* __restrict__ ei, const float* __restrict__ ea,
                      const float* __restrict__ xin, const float* __restrict__ w_edge,
                      const int* __restrict__ ovf, const int* __restrict__ ovfcnt,
                      float* __restrict__ m, int E){
  int cnt = *ovfcnt; if (cnt > OVF_MAX) cnt = OVF_MAX;
  int nwaves = (gridDim.x * blockDim.x) >> 6;
  int wid = (int)((blockIdx.x*blockDim.x + threadIdx.x) >> 6);
  int d = threadIdx.x & 63;
  for (int k = wid; k < cnt; k += nwaves){
    int e = ovf[k];
    int s = ei[e], dst = ei[E + e];
    float4 v  = *(const float4*)(ea + (size_t)e*4);
    float4 wv = *(const float4*)(w_edge + d*4);
    float msg = xin[(size_t)s*64 + d] + v.x*wv.x + v.y*wv.y + v.z*wv.z + v.w*wv.w;
    atomicAdd(&m[(size_t)dst*64 + d], msg);
  }
}

// GRU cell via MFMA. Round-9: one BLOCK per 16-node tile, 4 waves; wave j
// owns output cols d in [16j,16j+16) = w-row-blocks {j, j+4, j+8}.
// A layout: A[m=lane&15][k=quad*8+j]; C/D: col=lane&15, row=quad*4+reg (m89/m91).
// __syncthreads() after fragment loads makes in-place (out==x) safe: writes
// are confined to own tile rows/cols, reads (full rows of tile) done first.
__global__ void __launch_bounds__(256) k_gru(
    const float* __restrict__ m, const float* x,
    const unsigned short* __restrict__ wih, const unsigned short* __restrict__ whh,
    const float* __restrict__ b_ih, const float* __restrict__ b_hh,
    float* out, int tiles, int N){
  int tile = blockIdx.x;
  if (tile >= tiles) return;
  int j    = threadIdx.x >> 6;        // output col-group 0..3
  int lane = threadIdx.x & 63;
  int col = lane & 15, quad = lane >> 4;
  int na = tile*16 + col; if (na > N-1) na = N-1;

  bf16x8 am[2], ax[2];
#pragma unroll
  for (int ks = 0; ks < 2; ++ks){
    int kb = ks*32 + quad*8;
    const float4* mp = (const float4*)(m + (size_t)na*64 + kb);
    float4 lo = mp[0], hi = mp[1];
    us8 tm;
    tm[0]=f2bf(lo.x); tm[1]=f2bf(lo.y); tm[2]=f2bf(lo.z); tm[3]=f2bf(lo.w);
    tm[4]=f2bf(hi.x); tm[5]=f2bf(hi.y); tm[6]=f2bf(hi.z); tm[7]=f2bf(hi.w);
    am[ks] = __builtin_bit_cast(bf16x8, tm);
    const float4* xp = (const float4*)(x + (size_t)na*64 + kb);
    float4 xlo = xp[0], xhi = xp[1];
    us8 tx;
    tx[0]=f2bf(xlo.x); tx[1]=f2bf(xlo.y); tx[2]=f2bf(xlo.z); tx[3]=f2bf(xlo.w);
    tx[4]=f2bf(xhi.x); tx[5]=f2bf(xhi.y); tx[6]=f2bf(xhi.z); tx[7]=f2bf(xhi.w);
    ax[ks] = __builtin_bit_cast(bf16x8, tx);
  }
  __syncthreads();   // all waves finished reading x rows (in-place layer 2)

  floatx4 ai[3], ah[3];   // row-blocks j (r-gate), j+4 (z), j+8 (n)
#pragma unroll
  for (int g = 0; g < 3; ++g){ ai[g] = (floatx4)0.f; ah[g] = (floatx4)0.f; }
#pragma unroll
  for (int g = 0; g < 3; ++g){
    int r = (g*4 + j)*16 + col;   // output row of w (0..191)
#pragma unroll
    for (int ks = 0; ks < 2; ++ks){
      int kb = ks*32 + quad*8;
      bf16x8 bi = __builtin_bit_cast(bf16x8, *(const us8*)(wih + (size_t)r*64 + kb));
      ai[g] = __builtin_amdgcn_mfma_f32_16x16x32_bf16(am[ks], bi, ai[g], 0,0,0);
      bf16x8 bh = __builtin_bit_cast(bf16x8, *(const us8*)(whh + (size_t)r*64 + kb));
      ah[g] = __builtin_amdgcn_mfma_f32_16x16x32_bf16(ax[ks], bh, ah[g], 0,0,0);
    }
  }

  int d = j*16 + col;
  float bir = b_ih[d],      bhr = b_hh[d];
  float biz = b_ih[64+d],   bhz = b_hh[64+d];
  float bin = b_ih[128+d],  bhn = b_hh[128+d];
#pragma unroll
  for (int rg = 0; rg < 4; ++rg){
    int node = tile*16 + quad*4 + rg;
    if (node >= N) continue;
    float rr = sigm(ai[0][rg] + bir + ah[0][rg] + bhr);
    float zz = sigm(ai[1][rg] + biz + ah[1][rg] + bhz);
    float nn = tanhf(ai[2][rg] + bin + rr*(ah[2][rg] + bhn));
    float xv = x[(size_t)node*64 + d];
    float hv = (1.f - zz)*nn + zz*xv;
    out[(size_t)node*64 + d] = fmaxf(hv, 0.f);
  }
}

// MoE round-9: one BLOCK per 16-node tile; wave e owns expert e (8 MFMAs),
// wave 0 additionally computes the gate logits. Combine via padded LDS.
__global__ void __launch_bounds__(256) k_moe(
    const float* __restrict__ h,
    const unsigned short* __restrict__ gate_w, const float* __restrict__ gate_b,
    const unsigned short* __restrict__ exp_w,  const float* __restrict__ exp_b,
    float* __restrict__ v_out, int tiles, int N){
  __shared__ float gsm[16][4];
  __shared__ float vsm[4][16][65];   // +1 pad: write banks spread across quads
  int tile = blockIdx.x;
  if (tile >= tiles) return;
  int e    = threadIdx.x >> 6;       // expert id 0..3
  int lane = threadIdx.x & 63;
  int col = lane & 15, quad = lane >> 4;
  int na = tile*16 + col; if (na > N-1) na = N-1;

  bf16x8 a[2];
#pragma unroll
  for (int ks=0; ks<2; ++ks){
    int kb = ks*32 + quad*8;
    const float4* hp = (const float4*)(h + (size_t)na*64 + kb);
    float4 lo = hp[0], hi = hp[1];
    us8 th;
    th[0]=f2bf(lo.x); th[1]=f2bf(lo.y); th[2]=f2bf(lo.z); th[3]=f2bf(lo.w);
    th[4]=f2bf(hi.x); th[5]=f2bf(hi.y); th[6]=f2bf(hi.z); th[7]=f2bf(hi.w);
    a[ks] = __builtin_bit_cast(bf16x8, th);
  }

  if (e == 0){   // gate logits for the tile
    floatx4 accg = (floatx4)0.f;
#pragma unroll
    for (int ks=0; ks<2; ++ks){
      int kb = ks*32 + quad*8;
      us8 braw = {0,0,0,0,0,0,0,0};
      if (col < 4) braw = *(const us8*)(gate_w + col*64 + kb);
      accg = __builtin_amdgcn_mfma_f32_16x16x32_bf16(a[ks], __builtin_bit_cast(bf16x8, braw), accg, 0,0,0);
    }
    if (col < 4){
      float gb = gate_b[col];
#pragma unroll
      for (int rg=0;rg<4;++rg) gsm[quad*4+rg][col] = accg[rg] + gb;
    }
  }

  floatx4 acc[4];
#pragma unroll
  for (int nt=0;nt<4;++nt) acc[nt] = (floatx4)0.f;
#pragma unroll
  for (int nt=0;nt<4;++nt)
#pragma unroll
    for (int ks=0;ks<2;++ks){
      int kb = ks*32 + quad*8;
      bf16x8 b = __builtin_bit_cast(bf16x8,
          *(const us8*)(exp_w + ((size_t)e*64 + nt*16 + col)*64 + kb));
      acc[nt] = __builtin_amdgcn_mfma_f32_16x16x32_bf16(a[ks], b, acc[nt], 0,0,0);
    }
  __syncthreads();   // gsm ready

#pragma unroll
  for (int rg=0; rg<4; ++rg){
    int nrow = quad*4 + rg;
    float g0=gsm[nrow][0], g1=gsm[nrow][1], g2=gsm[nrow][2], g3=gsm[nrow][3];
    float mx = fmaxf(fmaxf(g0,g1), fmaxf(g2,g3));
    float e0=__expf(g0-mx), e1=__expf(g1-mx), e2=__expf(g2-mx), e3=__expf(g3-mx);
    float we = ((e==0)?e0:(e==1)?e1:(e==2)?e2:e3) / (e0+e1+e2+e3);
#pragma unroll
    for (int nt=0;nt<4;++nt){
      int o = nt*16 + col;
      vsm[e][nrow][o] = we * fmaxf(acc[nt][rg] + exp_b[e*64 + o], 0.f);
    }
  }
  __syncthreads();   // vsm ready

  for (int idx = threadIdx.x; idx < 1024; idx += 256){
    int nrow = idx >> 6, o = idx & 63;
    int node = tile*16 + nrow;
    if (node < N)
      v_out[(size_t)node*64 + o] = vsm[0][nrow][o] + vsm[1][nrow][o]
                                 + vsm[2][nrow][o] + vsm[3][nrow][o];
  }
}

__device__ __forceinline__ int lower_bound_i(const int* __restrict__ a, int n, int key){
  int lo = 0, hi = n;
  while (lo < hi){ int mid = (lo + hi) >> 1; if (a[mid] < key) lo = mid + 1; else hi = mid; }
  return lo;
}

// stage 1: B*PS blocks; block (g,s) reduces 1/PS of graph g's nodes.
__global__ void __launch_bounds__(256) k_pool(
    const float* __restrict__ v, const int* __restrict__ batch, int N,
    float* __restrict__ partial){
  __shared__ float red[4][64];
  int g = blockIdx.x / PS, s = blockIdx.x % PS;
  int t = threadIdx.x, d = t & 63, r = t >> 6;
  int start = lower_bound_i(batch, N, g);
  int end   = lower_bound_i(batch, N, g + 1);
  int len = end - start;
  int per = (len + PS - 1) / PS;
  int s0 = start + s*per;
  int s1 = s0 + per; if (s1 > end) s1 = end;
  float acc = 0.f;
  for (int i = s0 + r; i < s1; i += 4)
    acc += v[(size_t)i*64 + d];
  red[r][d] = acc;
  __syncthreads();
  if (r == 0)
    partial[(size_t)blockIdx.x*64 + d] = red[0][d] + red[1][d] + red[2][d] + red[3][d];
}

// stage 2: B blocks; sum PS partials, mean, write emb twice + logits head.
__global__ void __launch_bounds__(64) k_head(
    const float* __restrict__ partial, const int* __restrict__ batch, int N, int B,
    const float* __restrict__ ldxb,
    const float* __restrict__ proj_w, const float* __restrict__ proj_b,
    const float* __restrict__ fc_w, const float* __restrict__ fc_b,
    float* __restrict__ out){
  __shared__ float ges[64];
  int b = blockIdx.x, d = threadIdx.x;
  int start = lower_bound_i(batch, N, b);
  int end   = lower_bound_i(batch, N, b + 1);
  float sum = 0.f;
#pragma unroll
  for (int s = 0; s < PS; ++s)
    sum += partial[((size_t)b*PS + s)*64 + d];
  float ge = sum / fmaxf((float)(end - start), 1.f);
  ges[d] = ge;
  out[(size_t)b*64 + d]                = ge;
  out[(size_t)B*64 + (size_t)b*64 + d] = ge;
  __syncthreads();
  if (d < 10){
    float acc = fc_b[d];
    float fl = ldxb[b];
    const float* fr = fc_w + d*164;
    for (int p = 0; p < 100; ++p) acc += (fl*proj_w[p] + proj_b[p]) * fr[p];
    for (int dd = 0; dd < 64; ++dd) acc += ges[dd]*fr[100 + dd];
    out[(size_t)B*128 + (size_t)b*10 + d] = acc;
  }
}

extern "C" void kernel_launch(void* const* d_in, const int* in_sizes, int n_in,
                              void* d_out, int out_size, void* d_ws, size_t ws_size,
                              hipStream_t stream){
  const float* x      = (const float*)d_in[0];
  const int*   ei     = (const int*)d_in[1];
  const float* ea     = (const float*)d_in[2];
  const int*   batch  = (const int*)d_in[3];
  const float* ldxb   = (const float*)d_in[4];
  const float* w_edge1= (const float*)d_in[5];
  const float* b_edge1= (const float*)d_in[6];
  const float* w_ih1  = (const float*)d_in[7];
  const float* w_hh1  = (const float*)d_in[8];
  const float* b_ih1  = (const float*)d_in[9];
  const float* b_hh1  = (const float*)d_in[10];
  const float* w_edge2= (const float*)d_in[11];
  const float* b_edge2= (const float*)d_in[12];
  const float* w_ih2  = (const float*)d_in[13];
  const float* w_hh2  = (const float*)d_in[14];
  const float* b_ih2  = (const float*)d_in[15];
  const float* b_hh2  = (const float*)d_in[16];
  const float* gate_w = (const float*)d_in[17];
  const float* gate_b = (const float*)d_in[18];
  const float* exp_w  = (const float*)d_in[19];
  const float* exp_b  = (const float*)d_in[20];
  const float* proj_w = (const float*)d_in[21];
  const float* proj_b = (const float*)d_in[22];
  const float* fc_w   = (const float*)d_in[23];
  const float* fc_b   = (const float*)d_in[24];
  float* out = (float*)d_out;

  int N = in_sizes[0] / 64;
  int E = in_sizes[1] / 2;
  int B = in_sizes[4];
  int tiles = (N + 15) / 16;
  int nTot = N * 64;

  // workspace layout (all segment sizes multiples of 16B)
  float*   m       = (float*)d_ws;                      // N*64 f32 (also MoE v)
  float*   h       = m + (size_t)nTot;                  // N*64 f32
  int*     bkt_src = (int*)(h + (size_t)nTot);          // N*64 i32  [(sub*N+n)*8+k]
  ushort4* bkt_ea  = (ushort4*)(bkt_src + (size_t)nTot);// N*64 ushort4 (bf16x4)
  int*     cur     = (int*)(bkt_ea + (size_t)nTot);     // 8*N i32   [sub*N+n]
  int*     ovfcnt  = cur + (size_t)N*8;                 // 4 i32 (padded)
  int*     ovf     = ovfcnt + 4;                        // OVF_MAX i32
  unsigned short* wbf = (unsigned short*)(ovf + OVF_MAX); // 65792 bf16
  float*   partial = (float*)(wbf + 65792);             // B*PS*64 f32
  unsigned short* wih1bf = wbf;
  unsigned short* whh1bf = wbf + 12288;
  unsigned short* wih2bf = wbf + 24576;
  unsigned short* whh2bf = wbf + 36864;
  unsigned short* gatebf = wbf + 49152;
  unsigned short* expbf  = wbf + 49408;

  dim3 blk(256);
  int edgeBlocks = (E + 255)/256;
  int nodeWaveBlocks = (N + 3)/4;       // one wave per node
  int N8 = N*8;
  int initBlocks = ((N8 > 65792 ? N8 : 65792) + 255)/256;

  k_init<<<initBlocks, blk, 0, stream>>>(w_ih1, w_hh1, w_ih2, w_hh2, gate_w, exp_w,
                                         wbf, cur, ovfcnt, N8);
  k_bucket<<<edgeBlocks, blk, 0, stream>>>(ei, ea, cur, bkt_src, bkt_ea, ovfcnt, ovf, E, N);
  // ---- layer 1 ----
  k_gather<<<nodeWaveBlocks, blk, 0, stream>>>(cur, bkt_src, bkt_ea, x, w_edge1, b_edge1, m, N);
  k_ovf<<<8, blk, 0, stream>>>(ei, ea, x, w_edge1, ovf, ovfcnt, m, E);
  k_gru<<<tiles, blk, 0, stream>>>(m, x, wih1bf, whh1bf, b_ih1, b_hh1, h, tiles, N);
  // ---- layer 2 (in-place h update; barrier after fragment loads, safe) ----
  k_gather<<<nodeWaveBlocks, blk, 0, stream>>>(cur, bkt_src, bkt_ea, h, w_edge2, b_edge2, m, N);
  k_ovf<<<8, blk, 0, stream>>>(ei, ea, h, w_edge2, ovf, ovfcnt, m, E);
  k_gru<<<tiles, blk, 0, stream>>>(m, h, wih2bf, whh2bf, b_ih2, b_hh2, h, tiles, N);
  // ---- MoE -> v (reuse m), two-stage segmented-mean pool + heads ----
  k_moe<<<tiles, blk, 0, stream>>>(h, gatebf, gate_b, expbf, exp_b, m, tiles, N);
  k_pool<<<B*PS, blk, 0, stream>>>(m, batch, N, partial);
  k_head<<<B, 64, 0, stream>>>(partial, batch, N, B, ldxb, proj_w, proj_b, fc_w, fc_b, out);
}

// Round 2
// 359.040 us; speedup vs baseline: 1.0185x; 1.0100x over previous
//
#include <hip/hip_runtime.h>
#include <stdint.h>

// ---------------------------------------------------------------------------
// GNNWithMoE: 2x GGNN(edge-embed + gather + GRU) -> soft MoE -> mean pool
// ALL float tensors fp32; ints int32; out fp32. GEMMs via bf16 MFMA.
//
// Round-10 (k_bucket write-amp fix; round-9 post-mortem: k_bucket is #1 at
// 52-59us with WRITE_SIZE=81MB vs ~11MB payload -> 2 dirty lines/edge):
//  * bucket slot = ONE int4 {src, ea01 bf16x2, ea23 bf16x2, pad}: one 16B
//    scatter store per edge (was 2 stores to 2 arrays = 2 lines/edge).
//  * k_bucket processes 2 edges/thread (512/block): 2x in-flight atomics+
//    stores per wave (latency-bound at 54% occupancy, VALUBusy 0.9%).
//  * k_gather reads the fused slot with a single 16B load.
// Round-9: k_gru/k_moe split 4 waves/tile (col-groups / expert-per-wave).
// Sub-bucket cap 8, ~Poisson(2) load; overflow -> k_ovf fallback (any input).
// Workspace (16B-aligned):
//   m[N*64] f32 | h[N*64] f32 | bkt[N*64] int4 | cur[8*N] i32 | ovfcnt[4] |
//   ovf[32768] | wbf[65792] bf16 | partial[B*PS*64] f32
// ---------------------------------------------------------------------------

#define SUBCAP 8
#define OVF_MAX 32768
#define PS 16   // pool splits per graph

typedef __bf16 bf16x8 __attribute__((ext_vector_type(8)));
typedef float floatx4 __attribute__((ext_vector_type(4)));
typedef unsigned short us8 __attribute__((ext_vector_type(8)));

__device__ __forceinline__ unsigned short f2bf(float f){
  union { float f; unsigned u; } c; c.f = f;
  unsigned r = c.u + 0x7FFFu + ((c.u >> 16) & 1u);
  return (unsigned short)(r >> 16);
}
__device__ __forceinline__ float bf2f(unsigned short u){
  union { unsigned u; float f; } c; c.u = ((unsigned)u) << 16; return c.f;
}
__device__ __forceinline__ float sigm(float x){ return 1.f/(1.f + __expf(-x)); }

// fused: weight fp32->bf16 conversion + zero cur/ovfcnt  (cur is 8*N)
__global__ void k_init(const float* __restrict__ s0, const float* __restrict__ s1,
                       const float* __restrict__ s2, const float* __restrict__ s3,
                       const float* __restrict__ s4, const float* __restrict__ s5,
                       unsigned short* __restrict__ dst,
                       int* __restrict__ cur, int* __restrict__ ovfcnt, int N8){
  int i = blockIdx.x*blockDim.x + threadIdx.x;
  if (i < N8) cur[i] = 0;
  if (i == 0){ ovfcnt[0] = 0; }
  if (i >= 65792) return;
  const float* s; int off;
  if      (i < 12288){ s = s0; off = i; }
  else if (i < 24576){ s = s1; off = i - 12288; }
  else if (i < 36864){ s = s2; off = i - 24576; }
  else if (i < 49152){ s = s3; off = i - 36864; }
  else if (i < 49408){ s = s4; off = i - 49152; }
  else               { s = s5; off = i - 49408; }
  dst[i] = f2bf(s[off]);
}

// one atomic per edge into an XCD-local sub-bucket (counter AND data lines
// owned by one XCD under round-robin block dispatch); fused int4 payload
// {src, ea01, ea23, 0}; 2 edges per thread for memory-level parallelism.
__global__ void k_bucket(const int* __restrict__ ei, const float* __restrict__ ea,
                         int* __restrict__ cur, int4* __restrict__ bkt,
                         int* __restrict__ ovfcnt, int* __restrict__ ovf,
                         int E, int N){
  int base = blockIdx.x*512;
  int sub = blockIdx.x & 7;          // ~XCD id under round-robin dispatch
#pragma unroll
  for (int half = 0; half < 2; ++half){
    int e = base + half*256 + threadIdx.x;
    if (e >= E) continue;
    int s = ei[e];
    int d = ei[E + e];
    size_t sb = (size_t)sub*N + d;
    int pos = atomicAdd(&cur[sb], 1);
    if (pos < SUBCAP){
      float4 v = *(const float4*)(ea + (size_t)e*4);
      int4 p;
      p.x = s;
      p.y = (int)(((unsigned)f2bf(v.y) << 16) | (unsigned)f2bf(v.x));
      p.z = (int)(((unsigned)f2bf(v.w) << 16) | (unsigned)f2bf(v.z));
      p.w = 0;
      bkt[sb*SUBCAP + pos] = p;
    } else {
      int o = atomicAdd(ovfcnt, 1);
      if (o < OVF_MAX) ovf[o] = e;
    }
  }
}

// one wave per node, lane=dim; lane d also owns bucket slot (sub=d>>3,k=d&7):
// m[n,d] = x[n,d] + (deg+1)*b_edge[d] + w_edge[d,:].sum_e(ea[e,:]) + sum_e x[src,d]
// (overflow edges' x/ea terms added later by k_ovf; their bias IS counted here)
__global__ void __launch_bounds__(256) k_gather(
    const int* __restrict__ cur, const int4* __restrict__ bkt,
    const float* __restrict__ xin,
    const float* __restrict__ w_edge, const float* __restrict__ b_edge,
    float* __restrict__ m, int N){
  int n = (int)(((long long)blockIdx.x*blockDim.x + threadIdx.x) >> 6);
  if (n >= N) return;
  int d = threadIdx.x & 63;
  int sub = d >> 3, k = d & 7;
  size_t sb = (size_t)sub*N + n;
  int myc = cur[sb];
  // degAll = sum of the 8 sub-counts (each lane group replicates its sub's count)
  int contrib = (k == 0) ? myc : 0;
#pragma unroll
  for (int off = 1; off < 64; off <<= 1) contrib += __shfl_xor(contrib, off);
  int degAll = contrib;

  bool valid = k < min(myc, SUBCAP);
  int src = 0;
  float esx = 0.f, esy = 0.f, esz = 0.f, esw = 0.f;
  if (valid){
    int4 p = bkt[sb*SUBCAP + k];
    src = p.x;
    esx = bf2f((unsigned short)(p.y & 0xffff));
    esy = bf2f((unsigned short)(((unsigned)p.y) >> 16));
    esz = bf2f((unsigned short)(p.z & 0xffff));
    esw = bf2f((unsigned short)(((unsigned)p.z) >> 16));
  }

  float4 wv = *(const float4*)(w_edge + d*4);
  float acc = xin[(size_t)n*64 + d] + (float)(degAll + 1) * b_edge[d];

  // x-row gather: wave-uniform ballot mask, ctz lane-extract, 4 loads in flight
  unsigned long long mm = __ballot(valid);
  while (mm){
    int l0 = (int)__builtin_ctzll(mm); mm &= mm - 1;
    int s0 = __shfl(src, l0);
    float a0 = xin[(size_t)s0*64 + d];
    float a1 = 0.f, a2 = 0.f, a3 = 0.f;
    if (mm){
      int l1 = (int)__builtin_ctzll(mm); mm &= mm - 1;
      int s1 = __shfl(src, l1);
      a1 = xin[(size_t)s1*64 + d];
      if (mm){
        int l2 = (int)__builtin_ctzll(mm); mm &= mm - 1;
        int s2 = __shfl(src, l2);
        a2 = xin[(size_t)s2*64 + d];
        if (mm){
          int l3 = (int)__builtin_ctzll(mm); mm &= mm - 1;
          int s3 = __shfl(src, l3);
          a3 = xin[(size_t)s3*64 + d];
        }
      }
    }
    acc += (a0 + a1) + (a2 + a3);
  }

  // butterfly-sum ea over all 64 lanes (invalid lanes contribute 0)
#pragma unroll
  for (int off = 1; off < 64; off <<= 1){
    esx += __shfl_xor(esx, off);
    esy += __shfl_xor(esy, off);
    esz += __shfl_xor(esz, off);
    esw += __shfl_xor(esw, off);
  }
  acc += esx*wv.x + esy*wv.y + esz*wv.z + esw*wv.w;
  m[(size_t)n*64 + d] = acc;
}

// fallback for sub-bucket-overflow edges (~1e2 expected): atomic scatter, no bias
__global__ void k_ovf(const int* __restrict__ ei, const float* __restrict__ ea,
                      const float* __restrict__ xin, const float* __restrict__ w_edge,
                      const int* __restrict__ ovf, const int* __restrict__ ovfcnt,
                      float* __restrict__ m, int E){
  int cnt = *ovfcnt; if (cnt > OVF_MAX) cnt = OVF_MAX;
  int nwaves = (gridDim.x * blockDim.x) >> 6;
  int wid = (int)((blockIdx.x*blockDim.x + threadIdx.x) >> 6);
  int d = threadIdx.x & 63;
  for (int k = wid; k < cnt; k += nwaves){
    int e = ovf[k];
    int s = ei[e], dst = ei[E + e];
    float4 v  = *(const float4*)(ea + (size_t)e*4);
    float4 wv = *(const float4*)(w_edge + d*4);
    float msg = xin[(size_t)s*64 + d] + v.x*wv.x + v.y*wv.y + v.z*wv.z + v.w*wv.w;
    atomicAdd(&m[(size_t)dst*64 + d], msg);
  }
}

// GRU cell via MFMA. One BLOCK per 16-node tile, 4 waves; wave j owns output
// cols d in [16j,16j+16) = w-row-blocks {j, j+4, j+8}.
// A layout: A[m=lane&15][k=quad*8+j]; C/D: col=lane&15, row=quad*4+reg (m89/m91).
// __syncthreads() after fragment loads makes in-place (out==x) safe.
__global__ void __launch_bounds__(256) k_gru(
    const float* __restrict__ m, const float* x,
    const unsigned short* __restrict__ wih, const unsigned short* __restrict__ whh,
    const float* __restrict__ b_ih, const float* __restrict__ b_hh,
    float* out, int tiles, int N){
  int tile = blockIdx.x;
  if (tile >= tiles) return;
  int j    = threadIdx.x >> 6;        // output col-group 0..3
  int lane = threadIdx.x & 63;
  int col = lane & 15, quad = lane >> 4;
  int na = tile*16 + col; if (na > N-1) na = N-1;

  bf16x8 am[2], ax[2];
#pragma unroll
  for (int ks = 0; ks < 2; ++ks){
    int kb = ks*32 + quad*8;
    const float4* mp = (const float4*)(m + (size_t)na*64 + kb);
    float4 lo = mp[0], hi = mp[1];
    us8 tm;
    tm[0]=f2bf(lo.x); tm[1]=f2bf(lo.y); tm[2]=f2bf(lo.z); tm[3]=f2bf(lo.w);
    tm[4]=f2bf(hi.x); tm[5]=f2bf(hi.y); tm[6]=f2bf(hi.z); tm[7]=f2bf(hi.w);
    am[ks] = __builtin_bit_cast(bf16x8, tm);
    const float4* xp = (const float4*)(x + (size_t)na*64 + kb);
    float4 xlo = xp[0], xhi = xp[1];
    us8 tx;
    tx[0]=f2bf(xlo.x); tx[1]=f2bf(xlo.y); tx[2]=f2bf(xlo.z); tx[3]=f2bf(xlo.w);
    tx[4]=f2bf(xhi.x); tx[5]=f2bf(xhi.y); tx[6]=f2bf(xhi.z); tx[7]=f2bf(xhi.w);
    ax[ks] = __builtin_bit_cast(bf16x8, tx);
  }
  __syncthreads();   // all waves finished reading x rows (in-place layer 2)

  floatx4 ai[3], ah[3];   // row-blocks j (r-gate), j+4 (z), j+8 (n)
#pragma unroll
  for (int g = 0; g < 3; ++g){ ai[g] = (floatx4)0.f; ah[g] = (floatx4)0.f; }
#pragma unroll
  for (int g = 0; g < 3; ++g){
    int r = (g*4 + j)*16 + col;   // output row of w (0..191)
#pragma unroll
    for (int ks = 0; ks < 2; ++ks){
      int kb = ks*32 + quad*8;
      bf16x8 bi = __builtin_bit_cast(bf16x8, *(const us8*)(wih + (size_t)r*64 + kb));
      ai[g] = __builtin_amdgcn_mfma_f32_16x16x32_bf16(am[ks], bi, ai[g], 0,0,0);
      bf16x8 bh = __builtin_bit_cast(bf16x8, *(const us8*)(whh + (size_t)r*64 + kb));
      ah[g] = __builtin_amdgcn_mfma_f32_16x16x32_bf16(ax[ks], bh, ah[g], 0,0,0);
    }
  }

  int d = j*16 + col;
  float bir = b_ih[d],      bhr = b_hh[d];
  float biz = b_ih[64+d],   bhz = b_hh[64+d];
  float bin = b_ih[128+d],  bhn = b_hh[128+d];
#pragma unroll
  for (int rg = 0; rg < 4; ++rg){
    int node = tile*16 + quad*4 + rg;
    if (node >= N) continue;
    float rr = sigm(ai[0][rg] + bir + ah[0][rg] + bhr);
    float zz = sigm(ai[1][rg] + biz + ah[1][rg] + bhz);
    float nn = tanhf(ai[2][rg] + bin + rr*(ah[2][rg] + bhn));
    float xv = x[(size_t)node*64 + d];
    float hv = (1.f - zz)*nn + zz*xv;
    out[(size_t)node*64 + d] = fmaxf(hv, 0.f);
  }
}

// MoE: one BLOCK per 16-node tile; wave e owns expert e (8 MFMAs),
// wave 0 additionally computes the gate logits. Combine via padded LDS.
__global__ void __launch_bounds__(256) k_moe(
    const float* __restrict__ h,
    const unsigned short* __restrict__ gate_w, const float* __restrict__ gate_b,
    const unsigned short* __restrict__ exp_w,  const float* __restrict__ exp_b,
    float* __restrict__ v_out, int tiles, int N){
  __shared__ float gsm[16][4];
  __shared__ float vsm[4][16][65];   // +1 pad: write banks spread across quads
  int tile = blockIdx.x;
  if (tile >= tiles) return;
  int e    = threadIdx.x >> 6;       // expert id 0..3
  int lane = threadIdx.x & 63;
  int col = lane & 15, quad = lane >> 4;
  int na = tile*16 + col; if (na > N-1) na = N-1;

  bf16x8 a[2];
#pragma unroll
  for (int ks=0; ks<2; ++ks){
    int kb = ks*32 + quad*8;
    const float4* hp = (const float4*)(h + (size_t)na*64 + kb);
    float4 lo = hp[0], hi = hp[1];
    us8 th;
    th[0]=f2bf(lo.x); th[1]=f2bf(lo.y); th[2]=f2bf(lo.z); th[3]=f2bf(lo.w);
    th[4]=f2bf(hi.x); th[5]=f2bf(hi.y); th[6]=f2bf(hi.z); th[7]=f2bf(hi.w);
    a[ks] = __builtin_bit_cast(bf16x8, th);
  }

  if (e == 0){   // gate logits for the tile
    floatx4 accg = (floatx4)0.f;
#pragma unroll
    for (int ks=0; ks<2; ++ks){
      int kb = ks*32 + quad*8;
      us8 braw = {0,0,0,0,0,0,0,0};
      if (col < 4) braw = *(const us8*)(gate_w + col*64 + kb);
      accg = __builtin_amdgcn_mfma_f32_16x16x32_bf16(a[ks], __builtin_bit_cast(bf16x8, braw), accg, 0,0,0);
    }
    if (col < 4){
      float gb = gate_b[col];
#pragma unroll
      for (int rg=0;rg<4;++rg) gsm[quad*4+rg][col] = accg[rg] + gb;
    }
  }

  floatx4 acc[4];
#pragma unroll
  for (int nt=0;nt<4;++nt) acc[nt] = (floatx4)0.f;
#pragma unroll
  for (int nt=0;nt<4;++nt)
#pragma unroll
    for (int ks=0;ks<2;++ks){
      int kb = ks*32 + quad*8;
      bf16x8 b = __builtin_bit_cast(bf16x8,
          *(const us8*)(exp_w + ((size_t)e*64 + nt*16 + col)*64 + kb));
      acc[nt] = __builtin_amdgcn_mfma_f32_16x16x32_bf16(a[ks], b, acc[nt], 0,0,0);
    }
  __syncthreads();   // gsm ready

#pragma unroll
  for (int rg=0; rg<4; ++rg){
    int nrow = quad*4 + rg;
    float g0=gsm[nrow][0], g1=gsm[nrow][1], g2=gsm[nrow][2], g3=gsm[nrow][3];
    float mx = fmaxf(fmaxf(g0,g1), fmaxf(g2,g3));
    float e0=__expf(g0-mx), e1=__expf(g1-mx), e2=__expf(g2-mx), e3=__expf(g3-mx);
    float we = ((e==0)?e0:(e==1)?e1:(e==2)?e2:e3) / (e0+e1+e2+e3);
#pragma unroll
    for (int nt=0;nt<4;++nt){
      int o = nt*16 + col;
      vsm[e][nrow][o] = we * fmaxf(acc[nt][rg] + exp_b[e*64 + o], 0.f);
    }
  }
  __syncthreads();   // vsm ready

  for (int idx = threadIdx.x; idx < 1024; idx += 256){
    int nrow = idx >> 6, o = idx & 63;
    int node = tile*16 + nrow;
    if (node < N)
      v_out[(size_t)node*64 + o] = vsm[0][nrow][o] + vsm[1][nrow][o]
                                 + vsm[2][nrow][o] + vsm[3][nrow][o];
  }
}

__device__ __forceinline__ int lower_bound_i(const int* __restrict__ a, int n, int key){
  int lo = 0, hi = n;
  while (lo < hi){ int mid = (lo + hi) >> 1; if (a[mid] < key) lo = mid + 1; else hi = mid; }
  return lo;
}

// stage 1: B*PS blocks; block (g,s) reduces 1/PS of graph g's nodes.
__global__ void __launch_bounds__(256) k_pool(
    const float* __restrict__ v, const int* __restrict__ batch, int N,
    float* __restrict__ partial){
  __shared__ float red[4][64];
  int g = blockIdx.x / PS, s = blockIdx.x % PS;
  int t = threadIdx.x, d = t & 63, r = t >> 6;
  int start = lower_bound_i(batch, N, g);
  int end   = lower_bound_i(batch, N, g + 1);
  int len = end - start;
  int per = (len + PS - 1) / PS;
  int s0 = start + s*per;
  int s1 = s0 + per; if (s1 > end) s1 = end;
  float acc = 0.f;
  for (int i = s0 + r; i < s1; i += 4)
    acc += v[(size_t)i*64 + d];
  red[r][d] = acc;
  __syncthreads();
  if (r == 0)
    partial[(size_t)blockIdx.x*64 + d] = red[0][d] + red[1][d] + red[2][d] + red[3][d];
}

// stage 2: B blocks; sum PS partials, mean, write emb twice + logits head.
__global__ void __launch_bounds__(64) k_head(
    const float* __restrict__ partial, const int* __restrict__ batch, int N, int B,
    const float* __restrict__ ldxb,
    const float* __restrict__ proj_w, const float* __restrict__ proj_b,
    const float* __restrict__ fc_w, const float* __restrict__ fc_b,
    float* __restrict__ out){
  __shared__ float ges[64];
  int b = blockIdx.x, d = threadIdx.x;
  int start = lower_bound_i(batch, N, b);
  int end   = lower_bound_i(batch, N, b + 1);
  float sum = 0.f;
#pragma unroll
  for (int s = 0; s < PS; ++s)
    sum += partial[((size_t)b*PS + s)*64 + d];
  float ge = sum / fmaxf((float)(end - start), 1.f);
  ges[d] = ge;
  out[(size_t)b*64 + d]                = ge;
  out[(size_t)B*64 + (size_t)b*64 + d] = ge;
  __syncthreads();
  if (d < 10){
    float acc = fc_b[d];
    float fl = ldxb[b];
    const float* fr = fc_w + d*164;
    for (int p = 0; p < 100; ++p) acc += (fl*proj_w[p] + proj_b[p]) * fr[p];
    for (int dd = 0; dd < 64; ++dd) acc += ges[dd]*fr[100 + dd];
    out[(size_t)B*128 + (size_t)b*10 + d] = acc;
  }
}

extern "C" void kernel_launch(void* const* d_in, const int* in_sizes, int n_in,
                              void* d_out, int out_size, void* d_ws, size_t ws_size,
                              hipStream_t stream){
  const float* x      = (const float*)d_in[0];
  const int*   ei     = (const int*)d_in[1];
  const float* ea     = (const float*)d_in[2];
  const int*   batch  = (const int*)d_in[3];
  const float* ldxb   = (const float*)d_in[4];
  const float* w_edge1= (const float*)d_in[5];
  const float* b_edge1= (const float*)d_in[6];
  const float* w_ih1  = (const float*)d_in[7];
  const float* w_hh1  = (const float*)d_in[8];
  const float* b_ih1  = (const float*)d_in[9];
  const float* b_hh1  = (const float*)d_in[10];
  const float* w_edge2= (const float*)d_in[11];
  const float* b_edge2= (const float*)d_in[12];
  const float* w_ih2  = (const float*)d_in[13];
  const float* w_hh2  = (const float*)d_in[14];
  const float* b_ih2  = (const float*)d_in[15];
  const float* b_hh2  = (const float*)d_in[16];
  const float* gate_w = (const float*)d_in[17];
  const float* gate_b = (const float*)d_in[18];
  const float* exp_w  = (const float*)d_in[19];
  const float* exp_b  = (const float*)d_in[20];
  const float* proj_w = (const float*)d_in[21];
  const float* proj_b = (const float*)d_in[22];
  const float* fc_w   = (const float*)d_in[23];
  const float* fc_b   = (const float*)d_in[24];
  float* out = (float*)d_out;

  int N = in_sizes[0] / 64;
  int E = in_sizes[1] / 2;
  int B = in_sizes[4];
  int tiles = (N + 15) / 16;
  int nTot = N * 64;

  // workspace layout (all segment sizes multiples of 16B)
  float*   m       = (float*)d_ws;                      // N*64 f32 (also MoE v)
  float*   h       = m + (size_t)nTot;                  // N*64 f32
  int4*    bkt     = (int4*)(h + (size_t)nTot);         // N*64 int4 {src,ea01,ea23,0}
  int*     cur     = (int*)(bkt + (size_t)nTot);        // 8*N i32   [sub*N+n]
  int*     ovfcnt  = cur + (size_t)N*8;                 // 4 i32 (padded)
  int*     ovf     = ovfcnt + 4;                        // OVF_MAX i32
  unsigned short* wbf = (unsigned short*)(ovf + OVF_MAX); // 65792 bf16
  float*   partial = (float*)(wbf + 65792);             // B*PS*64 f32
  unsigned short* wih1bf = wbf;
  unsigned short* whh1bf = wbf + 12288;
  unsigned short* wih2bf = wbf + 24576;
  unsigned short* whh2bf = wbf + 36864;
  unsigned short* gatebf = wbf + 49152;
  unsigned short* expbf  = wbf + 49408;

  dim3 blk(256);
  int edgeBlocks = (E + 511)/512;       // 2 edges per thread
  int nodeWaveBlocks = (N + 3)/4;       // one wave per node
  int N8 = N*8;
  int initBlocks = ((N8 > 65792 ? N8 : 65792) + 255)/256;

  k_init<<<initBlocks, blk, 0, stream>>>(w_ih1, w_hh1, w_ih2, w_hh2, gate_w, exp_w,
                                         wbf, cur, ovfcnt, N8);
  k_bucket<<<edgeBlocks, blk, 0, stream>>>(ei, ea, cur, bkt, ovfcnt, ovf, E, N);
  // ---- layer 1 ----
  k_gather<<<nodeWaveBlocks, blk, 0, stream>>>(cur, bkt, x, w_edge1, b_edge1, m, N);
  k_ovf<<<8, blk, 0, stream>>>(ei, ea, x, w_edge1, ovf, ovfcnt, m, E);
  k_gru<<<tiles, blk, 0, stream>>>(m, x, wih1bf, whh1bf, b_ih1, b_hh1, h, tiles, N);
  // ---- layer 2 (in-place h update; barrier after fragment loads, safe) ----
  k_gather<<<nodeWaveBlocks, blk, 0, stream>>>(cur, bkt, h, w_edge2, b_edge2, m, N);
  k_ovf<<<8, blk, 0, stream>>>(ei, ea, h, w_edge2, ovf, ovfcnt, m, E);
  k_gru<<<tiles, blk, 0, stream>>>(m, h, wih2bf, whh2bf, b_ih2, b_hh2, h, tiles, N);
  // ---- MoE -> v (reuse m), two-stage segmented-mean pool + heads ----
  k_moe<<<tiles, blk, 0, stream>>>(h, gatebf, gate_b, expbf, exp_b, m, tiles, N);
  k_pool<<<B*PS, blk, 0, stream>>>(m, batch, N, partial);
  k_head<<<B, 64, 0, stream>>>(partial, batch, N, B, ldxb, proj_w, proj_b, fc_w, fc_b, out);
}

// Round 3
// 354.302 us; speedup vs baseline: 1.0321x; 1.0134x over previous
//
#include <hip/hip_runtime.h>
#include <stdint.h>

// ---------------------------------------------------------------------------
// GNNWithMoE: 2x GGNN(edge-embed + gather + GRU) -> soft MoE -> mean pool
// ALL float tensors fp32; ints int32; out fp32. GEMMs via bf16 MFMA.
//
// Round-11 (atomic-latency fix; round-10 post-mortem: WRITE_SIZE halved as
// predicted but dur flat -> the wall is 800k device-scope atomicAdd round
// trips (~700cy to coherent fabric), rate = Q_miss/L ~ 15G/s):
//  * k_bucket: sub = PHYSICAL XCD id (s_getreg hwreg(HW_REG_XCC_ID), m09) ->
//    every touch of cur[sub*N+d] goes through that XCD's TCC. Counter atomic
//    dropped to __HIP_MEMORY_SCOPE_WORKGROUP: executes at local TCC (~200cy).
//    Correct by physical routing, NOT by dispatch heuristic. ovfcnt stays
//    device-scope. bkt payload lines also XCD-local now.
//  * k_gather: 8-wide ballot/ctz extraction (was 4): 2 iters @ deg~16,
//    2x row-load MLP.
// Round-10: fused int4 bucket slot {src, ea01, ea23, pad}, 2 edges/thread.
// Round-9: k_gru/k_moe split 4 waves/tile (col-groups / expert-per-wave).
// Sub-bucket cap 8, ~Poisson(2) load; overflow -> k_ovf fallback (any input).
// Workspace (16B-aligned):
//   m[N*64] f32 | h[N*64] f32 | bkt[N*64] int4 | cur[8*N] i32 | ovfcnt[4] |
//   ovf[32768] | wbf[65792] bf16 | partial[B*PS*64] f32
// ---------------------------------------------------------------------------

#define SUBCAP 8
#define OVF_MAX 32768
#define PS 16   // pool splits per graph

typedef __bf16 bf16x8 __attribute__((ext_vector_type(8)));
typedef float floatx4 __attribute__((ext_vector_type(4)));
typedef unsigned short us8 __attribute__((ext_vector_type(8)));

__device__ __forceinline__ unsigned short f2bf(float f){
  union { float f; unsigned u; } c; c.f = f;
  unsigned r = c.u + 0x7FFFu + ((c.u >> 16) & 1u);
  return (unsigned short)(r >> 16);
}
__device__ __forceinline__ float bf2f(unsigned short u){
  union { unsigned u; float f; } c; c.u = ((unsigned)u) << 16; return c.f;
}
__device__ __forceinline__ float sigm(float x){ return 1.f/(1.f + __expf(-x)); }

// fused: weight fp32->bf16 conversion + zero cur/ovfcnt  (cur is 8*N)
__global__ void k_init(const float* __restrict__ s0, const float* __restrict__ s1,
                       const float* __restrict__ s2, const float* __restrict__ s3,
                       const float* __restrict__ s4, const float* __restrict__ s5,
                       unsigned short* __restrict__ dst,
                       int* __restrict__ cur, int* __restrict__ ovfcnt, int N8){
  int i = blockIdx.x*blockDim.x + threadIdx.x;
  if (i < N8) cur[i] = 0;
  if (i == 0){ ovfcnt[0] = 0; }
  if (i >= 65792) return;
  const float* s; int off;
  if      (i < 12288){ s = s0; off = i; }
  else if (i < 24576){ s = s1; off = i - 12288; }
  else if (i < 36864){ s = s2; off = i - 24576; }
  else if (i < 49152){ s = s3; off = i - 36864; }
  else if (i < 49408){ s = s4; off = i - 49152; }
  else               { s = s5; off = i - 49408; }
  dst[i] = f2bf(s[off]);
}

// sub-bucket = PHYSICAL XCD id: all touches of cur[sub*N+d] and the bkt data
// lines route through that XCD's TCC, so the counter atomic can legally run
// at WORKGROUP scope (local-L2 execution, ~200cy vs ~700cy device-scope).
// Fused int4 payload {src, ea01, ea23, 0}; 2 edges/thread for MLP.
__global__ void k_bucket(const int* __restrict__ ei, const float* __restrict__ ea,
                         int* __restrict__ cur, int4* __restrict__ bkt,
                         int* __restrict__ ovfcnt, int* __restrict__ ovf,
                         int E, int N){
  unsigned xcc;
  asm volatile("s_getreg_b32 %0, hwreg(HW_REG_XCC_ID)" : "=s"(xcc));
  int sub = (int)(xcc & 7u);         // physical XCD id (m09: 0..7)
  int base = blockIdx.x*512;
#pragma unroll
  for (int half = 0; half < 2; ++half){
    int e = base + half*256 + threadIdx.x;
    if (e >= E) continue;
    int s = ei[e];
    int d = ei[E + e];
    size_t sb = (size_t)sub*N + d;
    int pos = __hip_atomic_fetch_add(&cur[sb], 1, __ATOMIC_RELAXED,
                                     __HIP_MEMORY_SCOPE_WORKGROUP);
    if (pos < SUBCAP){
      float4 v = *(const float4*)(ea + (size_t)e*4);
      int4 p;
      p.x = s;
      p.y = (int)(((unsigned)f2bf(v.y) << 16) | (unsigned)f2bf(v.x));
      p.z = (int)(((unsigned)f2bf(v.w) << 16) | (unsigned)f2bf(v.z));
      p.w = 0;
      bkt[sb*SUBCAP + pos] = p;
    } else {
      int o = atomicAdd(ovfcnt, 1);   // cross-XCD counter: stays device scope
      if (o < OVF_MAX) ovf[o] = e;
    }
  }
}

// one wave per node, lane=dim; lane d also owns bucket slot (sub=d>>3,k=d&7):
// m[n,d] = x[n,d] + (deg+1)*b_edge[d] + w_edge[d,:].sum_e(ea[e,:]) + sum_e x[src,d]
// (overflow edges' x/ea terms added later by k_ovf; their bias IS counted here)
__global__ void __launch_bounds__(256) k_gather(
    const int* __restrict__ cur, const int4* __restrict__ bkt,
    const float* __restrict__ xin,
    const float* __restrict__ w_edge, const float* __restrict__ b_edge,
    float* __restrict__ m, int N){
  int n = (int)(((long long)blockIdx.x*blockDim.x + threadIdx.x) >> 6);
  if (n >= N) return;
  int d = threadIdx.x & 63;
  int sub = d >> 3, k = d & 7;
  size_t sb = (size_t)sub*N + n;
  int myc = cur[sb];
  // degAll = sum of the 8 sub-counts (each lane group replicates its sub's count)
  int contrib = (k == 0) ? myc : 0;
#pragma unroll
  for (int off = 1; off < 64; off <<= 1) contrib += __shfl_xor(contrib, off);
  int degAll = contrib;

  bool valid = k < min(myc, SUBCAP);
  int src = 0;
  float esx = 0.f, esy = 0.f, esz = 0.f, esw = 0.f;
  if (valid){
    int4 p = bkt[sb*SUBCAP + k];
    src = p.x;
    esx = bf2f((unsigned short)(p.y & 0xffff));
    esy = bf2f((unsigned short)(((unsigned)p.y) >> 16));
    esz = bf2f((unsigned short)(p.z & 0xffff));
    esw = bf2f((unsigned short)(((unsigned)p.z) >> 16));
  }

  float4 wv = *(const float4*)(w_edge + d*4);
  float acc = xin[(size_t)n*64 + d] + (float)(degAll + 1) * b_edge[d];

  // x-row gather: wave-uniform ballot mask, ctz lane-extract, 8 loads in flight
  unsigned long long mm = __ballot(valid);
  while (mm){
    float a0=0.f,a1=0.f,a2=0.f,a3=0.f,a4=0.f,a5=0.f,a6=0.f,a7=0.f;
    {
      int l0 = (int)__builtin_ctzll(mm); mm &= mm - 1;
      a0 = xin[(size_t)__shfl(src, l0)*64 + d];
      if (mm){
        int l1 = (int)__builtin_ctzll(mm); mm &= mm - 1;
        a1 = xin[(size_t)__shfl(src, l1)*64 + d];
        if (mm){
          int l2 = (int)__builtin_ctzll(mm); mm &= mm - 1;
          a2 = xin[(size_t)__shfl(src, l2)*64 + d];
          if (mm){
            int l3 = (int)__builtin_ctzll(mm); mm &= mm - 1;
            a3 = xin[(size_t)__shfl(src, l3)*64 + d];
            if (mm){
              int l4 = (int)__builtin_ctzll(mm); mm &= mm - 1;
              a4 = xin[(size_t)__shfl(src, l4)*64 + d];
              if (mm){
                int l5 = (int)__builtin_ctzll(mm); mm &= mm - 1;
                a5 = xin[(size_t)__shfl(src, l5)*64 + d];
                if (mm){
                  int l6 = (int)__builtin_ctzll(mm); mm &= mm - 1;
                  a6 = xin[(size_t)__shfl(src, l6)*64 + d];
                  if (mm){
                    int l7 = (int)__builtin_ctzll(mm); mm &= mm - 1;
                    a7 = xin[(size_t)__shfl(src, l7)*64 + d];
                  }
                }
              }
            }
          }
        }
      }
    }
    acc += ((a0 + a1) + (a2 + a3)) + ((a4 + a5) + (a6 + a7));
  }

  // butterfly-sum ea over all 64 lanes (invalid lanes contribute 0)
#pragma unroll
  for (int off = 1; off < 64; off <<= 1){
    esx += __shfl_xor(esx, off);
    esy += __shfl_xor(esy, off);
    esz += __shfl_xor(esz, off);
    esw += __shfl_xor(esw, off);
  }
  acc += esx*wv.x + esy*wv.y + esz*wv.z + esw*wv.w;
  m[(size_t)n*64 + d] = acc;
}

// fallback for sub-bucket-overflow edges (~1e2 expected): atomic scatter, no bias
__global__ void k_ovf(const int* __restrict__ ei, const float* __restrict__ ea,
                      const float* __restrict__ xin, const float* __restrict__ w_edge,
                      const int* __restrict__ ovf, const int* __restrict__ ovfcnt,
                      float* __restrict__ m, int E){
  int cnt = *ovfcnt; if (cnt > OVF_MAX) cnt = OVF_MAX;
  int nwaves = (gridDim.x * blockDim.x) >> 6;
  int wid = (int)((blockIdx.x*blockDim.x + threadIdx.x) >> 6);
  int d = threadIdx.x & 63;
  for (int k = wid; k < cnt; k += nwaves){
    int e = ovf[k];
    int s = ei[e], dst = ei[E + e];
    float4 v  = *(const float4*)(ea + (size_t)e*4);
    float4 wv = *(const float4*)(w_edge + d*4);
    float msg = xin[(size_t)s*64 + d] + v.x*wv.x + v.y*wv.y + v.z*wv.z + v.w*wv.w;
    atomicAdd(&m[(size_t)dst*64 + d], msg);
  }
}

// GRU cell via MFMA. One BLOCK per 16-node tile, 4 waves; wave j owns output
// cols d in [16j,16j+16) = w-row-blocks {j, j+4, j+8}.
// A layout: A[m=lane&15][k=quad*8+j]; C/D: col=lane&15, row=quad*4+reg (m89/m91).
// __syncthreads() after fragment loads makes in-place (out==x) safe.
__global__ void __launch_bounds__(256) k_gru(
    const float* __restrict__ m, const float* x,
    const unsigned short* __restrict__ wih, const unsigned short* __restrict__ whh,
    const float* __restrict__ b_ih, const float* __restrict__ b_hh,
    float* out, int tiles, int N){
  int tile = blockIdx.x;
  if (tile >= tiles) return;
  int j    = threadIdx.x >> 6;        // output col-group 0..3
  int lane = threadIdx.x & 63;
  int col = lane & 15, quad = lane >> 4;
  int na = tile*16 + col; if (na > N-1) na = N-1;

  bf16x8 am[2], ax[2];
#pragma unroll
  for (int ks = 0; ks < 2; ++ks){
    int kb = ks*32 + quad*8;
    const float4* mp = (const float4*)(m + (size_t)na*64 + kb);
    float4 lo = mp[0], hi = mp[1];
    us8 tm;
    tm[0]=f2bf(lo.x); tm[1]=f2bf(lo.y); tm[2]=f2bf(lo.z); tm[3]=f2bf(lo.w);
    tm[4]=f2bf(hi.x); tm[5]=f2bf(hi.y); tm[6]=f2bf(hi.z); tm[7]=f2bf(hi.w);
    am[ks] = __builtin_bit_cast(bf16x8, tm);
    const float4* xp = (const float4*)(x + (size_t)na*64 + kb);
    float4 xlo = xp[0], xhi = xp[1];
    us8 tx;
    tx[0]=f2bf(xlo.x); tx[1]=f2bf(xlo.y); tx[2]=f2bf(xlo.z); tx[3]=f2bf(xlo.w);
    tx[4]=f2bf(xhi.x); tx[5]=f2bf(xhi.y); tx[6]=f2bf(xhi.z); tx[7]=f2bf(xhi.w);
    ax[ks] = __builtin_bit_cast(bf16x8, tx);
  }
  __syncthreads();   // all waves finished reading x rows (in-place layer 2)

  floatx4 ai[3], ah[3];   // row-blocks j (r-gate), j+4 (z), j+8 (n)
#pragma unroll
  for (int g = 0; g < 3; ++g){ ai[g] = (floatx4)0.f; ah[g] = (floatx4)0.f; }
#pragma unroll
  for (int g = 0; g < 3; ++g){
    int r = (g*4 + j)*16 + col;   // output row of w (0..191)
#pragma unroll
    for (int ks = 0; ks < 2; ++ks){
      int kb = ks*32 + quad*8;
      bf16x8 bi = __builtin_bit_cast(bf16x8, *(const us8*)(wih + (size_t)r*64 + kb));
      ai[g] = __builtin_amdgcn_mfma_f32_16x16x32_bf16(am[ks], bi, ai[g], 0,0,0);
      bf16x8 bh = __builtin_bit_cast(bf16x8, *(const us8*)(whh + (size_t)r*64 + kb));
      ah[g] = __builtin_amdgcn_mfma_f32_16x16x32_bf16(ax[ks], bh, ah[g], 0,0,0);
    }
  }

  int d = j*16 + col;
  float bir = b_ih[d],      bhr = b_hh[d];
  float biz = b_ih[64+d],   bhz = b_hh[64+d];
  float bin = b_ih[128+d],  bhn = b_hh[128+d];
#pragma unroll
  for (int rg = 0; rg < 4; ++rg){
    int node = tile*16 + quad*4 + rg;
    if (node >= N) continue;
    float rr = sigm(ai[0][rg] + bir + ah[0][rg] + bhr);
    float zz = sigm(ai[1][rg] + biz + ah[1][rg] + bhz);
    float nn = tanhf(ai[2][rg] + bin + rr*(ah[2][rg] + bhn));
    float xv = x[(size_t)node*64 + d];
    float hv = (1.f - zz)*nn + zz*xv;
    out[(size_t)node*64 + d] = fmaxf(hv, 0.f);
  }
}

// MoE: one BLOCK per 16-node tile; wave e owns expert e (8 MFMAs),
// wave 0 additionally computes the gate logits. Combine via padded LDS.
__global__ void __launch_bounds__(256) k_moe(
    const float* __restrict__ h,
    const unsigned short* __restrict__ gate_w, const float* __restrict__ gate_b,
    const unsigned short* __restrict__ exp_w,  const float* __restrict__ exp_b,
    float* __restrict__ v_out, int tiles, int N){
  __shared__ float gsm[16][4];
  __shared__ float vsm[4][16][65];   // +1 pad: write banks spread across quads
  int tile = blockIdx.x;
  if (tile >= tiles) return;
  int e    = threadIdx.x >> 6;       // expert id 0..3
  int lane = threadIdx.x & 63;
  int col = lane & 15, quad = lane >> 4;
  int na = tile*16 + col; if (na > N-1) na = N-1;

  bf16x8 a[2];
#pragma unroll
  for (int ks=0; ks<2; ++ks){
    int kb = ks*32 + quad*8;
    const float4* hp = (const float4*)(h + (size_t)na*64 + kb);
    float4 lo = hp[0], hi = hp[1];
    us8 th;
    th[0]=f2bf(lo.x); th[1]=f2bf(lo.y); th[2]=f2bf(lo.z); th[3]=f2bf(lo.w);
    th[4]=f2bf(hi.x); th[5]=f2bf(hi.y); th[6]=f2bf(hi.z); th[7]=f2bf(hi.w);
    a[ks] = __builtin_bit_cast(bf16x8, th);
  }

  if (e == 0){   // gate logits for the tile
    floatx4 accg = (floatx4)0.f;
#pragma unroll
    for (int ks=0; ks<2; ++ks){
      int kb = ks*32 + quad*8;
      us8 braw = {0,0,0,0,0,0,0,0};
      if (col < 4) braw = *(const us8*)(gate_w + col*64 + kb);
      accg = __builtin_amdgcn_mfma_f32_16x16x32_bf16(a[ks], __builtin_bit_cast(bf16x8, braw), accg, 0,0,0);
    }
    if (col < 4){
      float gb = gate_b[col];
#pragma unroll
      for (int rg=0;rg<4;++rg) gsm[quad*4+rg][col] = accg[rg] + gb;
    }
  }

  floatx4 acc[4];
#pragma unroll
  for (int nt=0;nt<4;++nt) acc[nt] = (floatx4)0.f;
#pragma unroll
  for (int nt=0;nt<4;++nt)
#pragma unroll
    for (int ks=0;ks<2;++ks){
      int kb = ks*32 + quad*8;
      bf16x8 b = __builtin_bit_cast(bf16x8,
          *(const us8*)(exp_w + ((size_t)e*64 + nt*16 + col)*64 + kb));
      acc[nt] = __builtin_amdgcn_mfma_f32_16x16x32_bf16(a[ks], b, acc[nt], 0,0,0);
    }
  __syncthreads();   // gsm ready

#pragma unroll
  for (int rg=0; rg<4; ++rg){
    int nrow = quad*4 + rg;
    float g0=gsm[nrow][0], g1=gsm[nrow][1], g2=gsm[nrow][2], g3=gsm[nrow][3];
    float mx = fmaxf(fmaxf(g0,g1), fmaxf(g2,g3));
    float e0=__expf(g0-mx), e1=__expf(g1-mx), e2=__expf(g2-mx), e3=__expf(g3-mx);
    float we = ((e==0)?e0:(e==1)?e1:(e==2)?e2:e3) / (e0+e1+e2+e3);
#pragma unroll
    for (int nt=0;nt<4;++nt){
      int o = nt*16 + col;
      vsm[e][nrow][o] = we * fmaxf(acc[nt][rg] + exp_b[e*64 + o], 0.f);
    }
  }
  __syncthreads();   // vsm ready

  for (int idx = threadIdx.x; idx < 1024; idx += 256){
    int nrow = idx >> 6, o = idx & 63;
    int node = tile*16 + nrow;
    if (node < N)
      v_out[(size_t)node*64 + o] = vsm[0][nrow][o] + vsm[1][nrow][o]
                                 + vsm[2][nrow][o] + vsm[3][nrow][o];
  }
}

__device__ __forceinline__ int lower_bound_i(const int* __restrict__ a, int n, int key){
  int lo = 0, hi = n;
  while (lo < hi){ int mid = (lo + hi) >> 1; if (a[mid] < key) lo = mid + 1; else hi = mid; }
  return lo;
}

// stage 1: B*PS blocks; block (g,s) reduces 1/PS of graph g's nodes.
__global__ void __launch_bounds__(256) k_pool(
    const float* __restrict__ v, const int* __restrict__ batch, int N,
    float* __restrict__ partial){
  __shared__ float red[4][64];
  int g = blockIdx.x / PS, s = blockIdx.x % PS;
  int t = threadIdx.x, d = t & 63, r = t >> 6;
  int start = lower_bound_i(batch, N, g);
  int end   = lower_bound_i(batch, N, g + 1);
  int len = end - start;
  int per = (len + PS - 1) / PS;
  int s0 = start + s*per;
  int s1 = s0 + per; if (s1 > end) s1 = end;
  float acc = 0.f;
  for (int i = s0 + r; i < s1; i += 4)
    acc += v[(size_t)i*64 + d];
  red[r][d] = acc;
  __syncthreads();
  if (r == 0)
    partial[(size_t)blockIdx.x*64 + d] = red[0][d] + red[1][d] + red[2][d] + red[3][d];
}

// stage 2: B blocks; sum PS partials, mean, write emb twice + logits head.
__global__ void __launch_bounds__(64) k_head(
    const float* __restrict__ partial, const int* __restrict__ batch, int N, int B,
    const float* __restrict__ ldxb,
    const float* __restrict__ proj_w, const float* __restrict__ proj_b,
    const float* __restrict__ fc_w, const float* __restrict__ fc_b,
    float* __restrict__ out){
  __shared__ float ges[64];
  int b = blockIdx.x, d = threadIdx.x;
  int start = lower_bound_i(batch, N, b);
  int end   = lower_bound_i(batch, N, b + 1);
  float sum = 0.f;
#pragma unroll
  for (int s = 0; s < PS; ++s)
    sum += partial[((size_t)b*PS + s)*64 + d];
  float ge = sum / fmaxf((float)(end - start), 1.f);
  ges[d] = ge;
  out[(size_t)b*64 + d]                = ge;
  out[(size_t)B*64 + (size_t)b*64 + d] = ge;
  __syncthreads();
  if (d < 10){
    float acc = fc_b[d];
    float fl = ldxb[b];
    const float* fr = fc_w + d*164;
    for (int p = 0; p < 100; ++p) acc += (fl*proj_w[p] + proj_b[p]) * fr[p];
    for (int dd = 0; dd < 64; ++dd) acc += ges[dd]*fr[100 + dd];
    out[(size_t)B*128 + (size_t)b*10 + d] = acc;
  }
}

extern "C" void kernel_launch(void* const* d_in, const int* in_sizes, int n_in,
                              void* d_out, int out_size, void* d_ws, size_t ws_size,
                              hipStream_t stream){
  const float* x      = (const float*)d_in[0];
  const int*   ei     = (const int*)d_in[1];
  const float* ea     = (const float*)d_in[2];
  const int*   batch  = (const int*)d_in[3];
  const float* ldxb   = (const float*)d_in[4];
  const float* w_edge1= (const float*)d_in[5];
  const float* b_edge1= (const float*)d_in[6];
  const float* w_ih1  = (const float*)d_in[7];
  const float* w_hh1  = (const float*)d_in[8];
  const float* b_ih1  = (const float*)d_in[9];
  const float* b_hh1  = (const float*)d_in[10];
  const float* w_edge2= (const float*)d_in[11];
  const float* b_edge2= (const float*)d_in[12];
  const float* w_ih2  = (const float*)d_in[13];
  const float* w_hh2  = (const float*)d_in[14];
  const float* b_ih2  = (const float*)d_in[15];
  const float* b_hh2  = (const float*)d_in[16];
  const float* gate_w = (const float*)d_in[17];
  const float* gate_b = (const float*)d_in[18];
  const float* exp_w  = (const float*)d_in[19];
  const float* exp_b  = (const float*)d_in[20];
  const float* proj_w = (const float*)d_in[21];
  const float* proj_b = (const float*)d_in[22];
  const float* fc_w   = (const float*)d_in[23];
  const float* fc_b   = (const float*)d_in[24];
  float* out = (float*)d_out;

  int N = in_sizes[0] / 64;
  int E = in_sizes[1] / 2;
  int B = in_sizes[4];
  int tiles = (N + 15) / 16;
  int nTot = N * 64;

  // workspace layout (all segment sizes multiples of 16B)
  float*   m       = (float*)d_ws;                      // N*64 f32 (also MoE v)
  float*   h       = m + (size_t)nTot;                  // N*64 f32
  int4*    bkt     = (int4*)(h + (size_t)nTot);         // N*64 int4 {src,ea01,ea23,0}
  int*     cur     = (int*)(bkt + (size_t)nTot);        // 8*N i32   [sub*N+n]
  int*     ovfcnt  = cur + (size_t)N*8;                 // 4 i32 (padded)
  int*     ovf     = ovfcnt + 4;                        // OVF_MAX i32
  unsigned short* wbf = (unsigned short*)(ovf + OVF_MAX); // 65792 bf16
  float*   partial = (float*)(wbf + 65792);             // B*PS*64 f32
  unsigned short* wih1bf = wbf;
  unsigned short* whh1bf = wbf + 12288;
  unsigned short* wih2bf = wbf + 24576;
  unsigned short* whh2bf = wbf + 36864;
  unsigned short* gatebf = wbf + 49152;
  unsigned short* expbf  = wbf + 49408;

  dim3 blk(256);
  int edgeBlocks = (E + 511)/512;       // 2 edges per thread
  int nodeWaveBlocks = (N + 3)/4;       // one wave per node
  int N8 = N*8;
  int initBlocks = ((N8 > 65792 ? N8 : 65792) + 255)/256;

  k_init<<<initBlocks, blk, 0, stream>>>(w_ih1, w_hh1, w_ih2, w_hh2, gate_w, exp_w,
                                         wbf, cur, ovfcnt, N8);
  k_bucket<<<edgeBlocks, blk, 0, stream>>>(ei, ea, cur, bkt, ovfcnt, ovf, E, N);
  // ---- layer 1 ----
  k_gather<<<nodeWaveBlocks, blk, 0, stream>>>(cur, bkt, x, w_edge1, b_edge1, m, N);
  k_ovf<<<8, blk, 0, stream>>>(ei, ea, x, w_edge1, ovf, ovfcnt, m, E);
  k_gru<<<tiles, blk, 0, stream>>>(m, x, wih1bf, whh1bf, b_ih1, b_hh1, h, tiles, N);
  // ---- layer 2 (in-place h update; barrier after fragment loads, safe) ----
  k_gather<<<nodeWaveBlocks, blk, 0, stream>>>(cur, bkt, h, w_edge2, b_edge2, m, N);
  k_ovf<<<8, blk, 0, stream>>>(ei, ea, h, w_edge2, ovf, ovfcnt, m, E);
  k_gru<<<tiles, blk, 0, stream>>>(m, h, wih2bf, whh2bf, b_ih2, b_hh2, h, tiles, N);
  // ---- MoE -> v (reuse m), two-stage segmented-mean pool + heads ----
  k_moe<<<tiles, blk, 0, stream>>>(h, gatebf, gate_b, expbf, exp_b, m, tiles, N);
  k_pool<<<B*PS, blk, 0, stream>>>(m, batch, N, partial);
  k_head<<<B, 64, 0, stream>>>(partial, batch, N, B, ldxb, proj_w, proj_b, fc_w, fc_b, out);
}

// Round 4
// 353.883 us; speedup vs baseline: 1.0333x; 1.0012x over previous
//
#include <hip/hip_runtime.h>
#include <hip/hip_fp16.h>
#include <stdint.h>

// ---------------------------------------------------------------------------
// GNNWithMoE: 2x GGNN(edge-embed + gather + GRU) -> soft MoE -> mean pool
// ALL float tensors fp32; ints int32; out fp32. GEMMs via bf16 MFMA.
//
// Round-12 (gather row-traffic halving; round-11 post-mortem: k_bucket is at
// the L2 atomic-RMW rate floor (~0.8/cy/XCD) -> parked. Dominant remaining
// cost = 2x k_gather random x-row reads, 204MB/layer):
//  * fp16 row mirrors: x16 (k_init converts x), h16 (k_gru layer-1 writes).
//    k_gather reads neighbor rows at 2B/lane -> 128B/row, half the random
//    line traffic. All accumulation stays fp32; fp16 rel-err 2^-11 is
//    negligible vs existing bf16-MFMA rounding (absmax unchanged).
// Round-11: k_bucket sub = physical XCC id, workgroup-scope counter atomic.
// Round-10: fused int4 bucket slot {src, ea01, ea23, pad}, 2 edges/thread.
// Round-9: k_gru/k_moe split 4 waves/tile (col-groups / expert-per-wave).
// Sub-bucket cap 8, ~Poisson(2) load; overflow -> k_ovf fallback (any input).
// Workspace (16B-aligned):
//   m[N*64] f32 | h[N*64] f32 | bkt[N*64] int4 | cur[8*N] i32 | ovfcnt[4] |
//   ovf[32768] | wbf[65792] bf16 | partial[B*PS*64] f32 | x16[N*64] fp16 |
//   h16[N*64] fp16
// ---------------------------------------------------------------------------

#define SUBCAP 8
#define OVF_MAX 32768
#define PS 16   // pool splits per graph

typedef __bf16 bf16x8 __attribute__((ext_vector_type(8)));
typedef float floatx4 __attribute__((ext_vector_type(4)));
typedef unsigned short us8 __attribute__((ext_vector_type(8)));

__device__ __forceinline__ unsigned short f2bf(float f){
  union { float f; unsigned u; } c; c.f = f;
  unsigned r = c.u + 0x7FFFu + ((c.u >> 16) & 1u);
  return (unsigned short)(r >> 16);
}
__device__ __forceinline__ float bf2f(unsigned short u){
  union { unsigned u; float f; } c; c.u = ((unsigned)u) << 16; return c.f;
}
__device__ __forceinline__ unsigned short f2h(float f){
  return __half_as_ushort(__float2half(f));
}
__device__ __forceinline__ float h2f(unsigned short u){
  return __half2float(__ushort_as_half(u));
}
__device__ __forceinline__ float sigm(float x){ return 1.f/(1.f + __expf(-x)); }

// fused: weight fp32->bf16 conversion + zero cur/ovfcnt + x -> fp16 mirror
__global__ void k_init(const float* __restrict__ s0, const float* __restrict__ s1,
                       const float* __restrict__ s2, const float* __restrict__ s3,
                       const float* __restrict__ s4, const float* __restrict__ s5,
                       unsigned short* __restrict__ dst,
                       int* __restrict__ cur, int* __restrict__ ovfcnt, int N8,
                       const float* __restrict__ xin, unsigned short* __restrict__ x16,
                       int nTot){
  int i = blockIdx.x*blockDim.x + threadIdx.x;
  if (i < N8) cur[i] = 0;
  if (i == 0){ ovfcnt[0] = 0; }
  int base = i*8;
  if (base < nTot){
    const float4* xp = (const float4*)(xin + base);
    float4 a = xp[0], b = xp[1];
    us8 t;
    t[0]=f2h(a.x); t[1]=f2h(a.y); t[2]=f2h(a.z); t[3]=f2h(a.w);
    t[4]=f2h(b.x); t[5]=f2h(b.y); t[6]=f2h(b.z); t[7]=f2h(b.w);
    *(us8*)(x16 + base) = t;
  }
  if (i >= 65792) return;
  const float* s; int off;
  if      (i < 12288){ s = s0; off = i; }
  else if (i < 24576){ s = s1; off = i - 12288; }
  else if (i < 36864){ s = s2; off = i - 24576; }
  else if (i < 49152){ s = s3; off = i - 36864; }
  else if (i < 49408){ s = s4; off = i - 49152; }
  else               { s = s5; off = i - 49408; }
  dst[i] = f2bf(s[off]);
}

// sub-bucket = PHYSICAL XCD id: counter + payload lines route through that
// XCD's TCC; counter atomic at workgroup scope. At the L2 atomic-RMW rate
// floor (~0.8/cy/XCD measured r10/r11) -- parked.
__global__ void k_bucket(const int* __restrict__ ei, const float* __restrict__ ea,
                         int* __restrict__ cur, int4* __restrict__ bkt,
                         int* __restrict__ ovfcnt, int* __restrict__ ovf,
                         int E, int N){
  unsigned xcc;
  asm volatile("s_getreg_b32 %0, hwreg(HW_REG_XCC_ID)" : "=s"(xcc));
  int sub = (int)(xcc & 7u);         // physical XCD id (m09: 0..7)
  int base = blockIdx.x*512;
#pragma unroll
  for (int half = 0; half < 2; ++half){
    int e = base + half*256 + threadIdx.x;
    if (e >= E) continue;
    int s = ei[e];
    int d = ei[E + e];
    size_t sb = (size_t)sub*N + d;
    int pos = __hip_atomic_fetch_add(&cur[sb], 1, __ATOMIC_RELAXED,
                                     __HIP_MEMORY_SCOPE_WORKGROUP);
    if (pos < SUBCAP){
      float4 v = *(const float4*)(ea + (size_t)e*4);
      int4 p;
      p.x = s;
      p.y = (int)(((unsigned)f2bf(v.y) << 16) | (unsigned)f2bf(v.x));
      p.z = (int)(((unsigned)f2bf(v.w) << 16) | (unsigned)f2bf(v.z));
      p.w = 0;
      bkt[sb*SUBCAP + pos] = p;
    } else {
      int o = atomicAdd(ovfcnt, 1);   // cross-XCD counter: stays device scope
      if (o < OVF_MAX) ovf[o] = e;
    }
  }
}

// one wave per node, lane=dim; lane d also owns bucket slot (sub=d>>3,k=d&7):
// m[n,d] = x[n,d] + (deg+1)*b_edge[d] + w_edge[d,:].sum_e(ea[e,:]) + sum_e x[src,d]
// neighbor rows read from the fp16 mirror (128B/row, half the line traffic).
__global__ void __launch_bounds__(256) k_gather(
    const int* __restrict__ cur, const int4* __restrict__ bkt,
    const float* __restrict__ xin, const unsigned short* __restrict__ x16,
    const float* __restrict__ w_edge, const float* __restrict__ b_edge,
    float* __restrict__ m, int N){
  int n = (int)(((long long)blockIdx.x*blockDim.x + threadIdx.x) >> 6);
  if (n >= N) return;
  int d = threadIdx.x & 63;
  int sub = d >> 3, k = d & 7;
  size_t sb = (size_t)sub*N + n;
  int myc = cur[sb];
  // degAll = sum of the 8 sub-counts (each lane group replicates its sub's count)
  int contrib = (k == 0) ? myc : 0;
#pragma unroll
  for (int off = 1; off < 64; off <<= 1) contrib += __shfl_xor(contrib, off);
  int degAll = contrib;

  bool valid = k < min(myc, SUBCAP);
  int src = 0;
  float esx = 0.f, esy = 0.f, esz = 0.f, esw = 0.f;
  if (valid){
    int4 p = bkt[sb*SUBCAP + k];
    src = p.x;
    esx = bf2f((unsigned short)(p.y & 0xffff));
    esy = bf2f((unsigned short)(((unsigned)p.y) >> 16));
    esz = bf2f((unsigned short)(p.z & 0xffff));
    esw = bf2f((unsigned short)(((unsigned)p.z) >> 16));
  }

  float4 wv = *(const float4*)(w_edge + d*4);
  float acc = xin[(size_t)n*64 + d] + (float)(degAll + 1) * b_edge[d];

  // x-row gather: wave-uniform ballot mask, ctz lane-extract, 8 loads in flight
  unsigned long long mm = __ballot(valid);
  while (mm){
    float a0=0.f,a1=0.f,a2=0.f,a3=0.f,a4=0.f,a5=0.f,a6=0.f,a7=0.f;
    {
      int l0 = (int)__builtin_ctzll(mm); mm &= mm - 1;
      a0 = h2f(x16[(size_t)__shfl(src, l0)*64 + d]);
      if (mm){
        int l1 = (int)__builtin_ctzll(mm); mm &= mm - 1;
        a1 = h2f(x16[(size_t)__shfl(src, l1)*64 + d]);
        if (mm){
          int l2 = (int)__builtin_ctzll(mm); mm &= mm - 1;
          a2 = h2f(x16[(size_t)__shfl(src, l2)*64 + d]);
          if (mm){
            int l3 = (int)__builtin_ctzll(mm); mm &= mm - 1;
            a3 = h2f(x16[(size_t)__shfl(src, l3)*64 + d]);
            if (mm){
              int l4 = (int)__builtin_ctzll(mm); mm &= mm - 1;
              a4 = h2f(x16[(size_t)__shfl(src, l4)*64 + d]);
              if (mm){
                int l5 = (int)__builtin_ctzll(mm); mm &= mm - 1;
                a5 = h2f(x16[(size_t)__shfl(src, l5)*64 + d]);
                if (mm){
                  int l6 = (int)__builtin_ctzll(mm); mm &= mm - 1;
                  a6 = h2f(x16[(size_t)__shfl(src, l6)*64 + d]);
                  if (mm){
                    int l7 = (int)__builtin_ctzll(mm); mm &= mm - 1;
                    a7 = h2f(x16[(size_t)__shfl(src, l7)*64 + d]);
                  }
                }
              }
            }
          }
        }
      }
    }
    acc += ((a0 + a1) + (a2 + a3)) + ((a4 + a5) + (a6 + a7));
  }

  // butterfly-sum ea over all 64 lanes (invalid lanes contribute 0)
#pragma unroll
  for (int off = 1; off < 64; off <<= 1){
    esx += __shfl_xor(esx, off);
    esy += __shfl_xor(esy, off);
    esz += __shfl_xor(esz, off);
    esw += __shfl_xor(esw, off);
  }
  acc += esx*wv.x + esy*wv.y + esz*wv.z + esw*wv.w;
  m[(size_t)n*64 + d] = acc;
}

// fallback for sub-bucket-overflow edges (~1e2 expected): atomic scatter, no bias
__global__ void k_ovf(const int* __restrict__ ei, const float* __restrict__ ea,
                      const float* __restrict__ xin, const float* __restrict__ w_edge,
                      const int* __restrict__ ovf, const int* __restrict__ ovfcnt,
                      float* __restrict__ m, int E){
  int cnt = *ovfcnt; if (cnt > OVF_MAX) cnt = OVF_MAX;
  int nwaves = (gridDim.x * blockDim.x) >> 6;
  int wid = (int)((blockIdx.x*blockDim.x + threadIdx.x) >> 6);
  int d = threadIdx.x & 63;
  for (int k = wid; k < cnt; k += nwaves){
    int e = ovf[k];
    int s = ei[e], dst = ei[E + e];
    float4 v  = *(const float4*)(ea + (size_t)e*4);
    float4 wv = *(const float4*)(w_edge + d*4);
    float msg = xin[(size_t)s*64 + d] + v.x*wv.x + v.y*wv.y + v.z*wv.z + v.w*wv.w;
    atomicAdd(&m[(size_t)dst*64 + d], msg);
  }
}

// GRU cell via MFMA. One BLOCK per 16-node tile, 4 waves; wave j owns output
// cols d in [16j,16j+16) = w-row-blocks {j, j+4, j+8}.
// A layout: A[m=lane&15][k=quad*8+j]; C/D: col=lane&15, row=quad*4+reg (m89/m91).
// __syncthreads() after fragment loads makes in-place (out==x) safe.
// h16out (nullable): fp16 mirror of the relu'd output for the next gather.
__global__ void __launch_bounds__(256) k_gru(
    const float* __restrict__ m, const float* x,
    const unsigned short* __restrict__ wih, const unsigned short* __restrict__ whh,
    const float* __restrict__ b_ih, const float* __restrict__ b_hh,
    float* out, unsigned short* h16out, int tiles, int N){
  int tile = blockIdx.x;
  if (tile >= tiles) return;
  int j    = threadIdx.x >> 6;        // output col-group 0..3
  int lane = threadIdx.x & 63;
  int col = lane & 15, quad = lane >> 4;
  int na = tile*16 + col; if (na > N-1) na = N-1;

  bf16x8 am[2], ax[2];
#pragma unroll
  for (int ks = 0; ks < 2; ++ks){
    int kb = ks*32 + quad*8;
    const float4* mp = (const float4*)(m + (size_t)na*64 + kb);
    float4 lo = mp[0], hi = mp[1];
    us8 tm;
    tm[0]=f2bf(lo.x); tm[1]=f2bf(lo.y); tm[2]=f2bf(lo.z); tm[3]=f2bf(lo.w);
    tm[4]=f2bf(hi.x); tm[5]=f2bf(hi.y); tm[6]=f2bf(hi.z); tm[7]=f2bf(hi.w);
    am[ks] = __builtin_bit_cast(bf16x8, tm);
    const float4* xp = (const float4*)(x + (size_t)na*64 + kb);
    float4 xlo = xp[0], xhi = xp[1];
    us8 tx;
    tx[0]=f2bf(xlo.x); tx[1]=f2bf(xlo.y); tx[2]=f2bf(xlo.z); tx[3]=f2bf(xlo.w);
    tx[4]=f2bf(xhi.x); tx[5]=f2bf(xhi.y); tx[6]=f2bf(xhi.z); tx[7]=f2bf(xhi.w);
    ax[ks] = __builtin_bit_cast(bf16x8, tx);
  }
  __syncthreads();   // all waves finished reading x rows (in-place layer 2)

  floatx4 ai[3], ah[3];   // row-blocks j (r-gate), j+4 (z), j+8 (n)
#pragma unroll
  for (int g = 0; g < 3; ++g){ ai[g] = (floatx4)0.f; ah[g] = (floatx4)0.f; }
#pragma unroll
  for (int g = 0; g < 3; ++g){
    int r = (g*4 + j)*16 + col;   // output row of w (0..191)
#pragma unroll
    for (int ks = 0; ks < 2; ++ks){
      int kb = ks*32 + quad*8;
      bf16x8 bi = __builtin_bit_cast(bf16x8, *(const us8*)(wih + (size_t)r*64 + kb));
      ai[g] = __builtin_amdgcn_mfma_f32_16x16x32_bf16(am[ks], bi, ai[g], 0,0,0);
      bf16x8 bh = __builtin_bit_cast(bf16x8, *(const us8*)(whh + (size_t)r*64 + kb));
      ah[g] = __builtin_amdgcn_mfma_f32_16x16x32_bf16(ax[ks], bh, ah[g], 0,0,0);
    }
  }

  int d = j*16 + col;
  float bir = b_ih[d],      bhr = b_hh[d];
  float biz = b_ih[64+d],   bhz = b_hh[64+d];
  float bin = b_ih[128+d],  bhn = b_hh[128+d];
#pragma unroll
  for (int rg = 0; rg < 4; ++rg){
    int node = tile*16 + quad*4 + rg;
    if (node >= N) continue;
    float rr = sigm(ai[0][rg] + bir + ah[0][rg] + bhr);
    float zz = sigm(ai[1][rg] + biz + ah[1][rg] + bhz);
    float nn = tanhf(ai[2][rg] + bin + rr*(ah[2][rg] + bhn));
    float xv = x[(size_t)node*64 + d];
    float hv = fmaxf((1.f - zz)*nn + zz*xv, 0.f);
    out[(size_t)node*64 + d] = hv;
    if (h16out) h16out[(size_t)node*64 + d] = f2h(hv);
  }
}

// MoE: one BLOCK per 16-node tile; wave e owns expert e (8 MFMAs),
// wave 0 additionally computes the gate logits. Combine via padded LDS.
__global__ void __launch_bounds__(256) k_moe(
    const float* __restrict__ h,
    const unsigned short* __restrict__ gate_w, const float* __restrict__ gate_b,
    const unsigned short* __restrict__ exp_w,  const float* __restrict__ exp_b,
    float* __restrict__ v_out, int tiles, int N){
  __shared__ float gsm[16][4];
  __shared__ float vsm[4][16][65];   // +1 pad: write banks spread across quads
  int tile = blockIdx.x;
  if (tile >= tiles) return;
  int e    = threadIdx.x >> 6;       // expert id 0..3
  int lane = threadIdx.x & 63;
  int col = lane & 15, quad = lane >> 4;
  int na = tile*16 + col; if (na > N-1) na = N-1;

  bf16x8 a[2];
#pragma unroll
  for (int ks=0; ks<2; ++ks){
    int kb = ks*32 + quad*8;
    const float4* hp = (const float4*)(h + (size_t)na*64 + kb);
    float4 lo = hp[0], hi = hp[1];
    us8 th;
    th[0]=f2bf(lo.x); th[1]=f2bf(lo.y); th[2]=f2bf(lo.z); th[3]=f2bf(lo.w);
    th[4]=f2bf(hi.x); th[5]=f2bf(hi.y); th[6]=f2bf(hi.z); th[7]=f2bf(hi.w);
    a[ks] = __builtin_bit_cast(bf16x8, th);
  }

  if (e == 0){   // gate logits for the tile
    floatx4 accg = (floatx4)0.f;
#pragma unroll
    for (int ks=0; ks<2; ++ks){
      int kb = ks*32 + quad*8;
      us8 braw = {0,0,0,0,0,0,0,0};
      if (col < 4) braw = *(const us8*)(gate_w + col*64 + kb);
      accg = __builtin_amdgcn_mfma_f32_16x16x32_bf16(a[ks], __builtin_bit_cast(bf16x8, braw), accg, 0,0,0);
    }
    if (col < 4){
      float gb = gate_b[col];
#pragma unroll
      for (int rg=0;rg<4;++rg) gsm[quad*4+rg][col] = accg[rg] + gb;
    }
  }

  floatx4 acc[4];
#pragma unroll
  for (int nt=0;nt<4;++nt) acc[nt] = (floatx4)0.f;
#pragma unroll
  for (int nt=0;nt<4;++nt)
#pragma unroll
    for (int ks=0;ks<2;++ks){
      int kb = ks*32 + quad*8;
      bf16x8 b = __builtin_bit_cast(bf16x8,
          *(const us8*)(exp_w + ((size_t)e*64 + nt*16 + col)*64 + kb));
      acc[nt] = __builtin_amdgcn_mfma_f32_16x16x32_bf16(a[ks], b, acc[nt], 0,0,0);
    }
  __syncthreads();   // gsm ready

#pragma unroll
  for (int rg=0; rg<4; ++rg){
    int nrow = quad*4 + rg;
    float g0=gsm[nrow][0], g1=gsm[nrow][1], g2=gsm[nrow][2], g3=gsm[nrow][3];
    float mx = fmaxf(fmaxf(g0,g1), fmaxf(g2,g3));
    float e0=__expf(g0-mx), e1=__expf(g1-mx), e2=__expf(g2-mx), e3=__expf(g3-mx);
    float we = ((e==0)?e0:(e==1)?e1:(e==2)?e2:e3) / (e0+e1+e2+e3);
#pragma unroll
    for (int nt=0;nt<4;++nt){
      int o = nt*16 + col;
      vsm[e][nrow][o] = we * fmaxf(acc[nt][rg] + exp_b[e*64 + o], 0.f);
    }
  }
  __syncthreads();   // vsm ready

  for (int idx = threadIdx.x; idx < 1024; idx += 256){
    int nrow = idx >> 6, o = idx & 63;
    int node = tile*16 + nrow;
    if (node < N)
      v_out[(size_t)node*64 + o] = vsm[0][nrow][o] + vsm[1][nrow][o]
                                 + vsm[2][nrow][o] + vsm[3][nrow][o];
  }
}

__device__ __forceinline__ int lower_bound_i(const int* __restrict__ a, int n, int key){
  int lo = 0, hi = n;
  while (lo < hi){ int mid = (lo + hi) >> 1; if (a[mid] < key) lo = mid + 1; else hi = mid; }
  return lo;
}

// stage 1: B*PS blocks; block (g,s) reduces 1/PS of graph g's nodes.
__global__ void __launch_bounds__(256) k_pool(
    const float* __restrict__ v, const int* __restrict__ batch, int N,
    float* __restrict__ partial){
  __shared__ float red[4][64];
  int g = blockIdx.x / PS, s = blockIdx.x % PS;
  int t = threadIdx.x, d = t & 63, r = t >> 6;
  int start = lower_bound_i(batch, N, g);
  int end   = lower_bound_i(batch, N, g + 1);
  int len = end - start;
  int per = (len + PS - 1) / PS;
  int s0 = start + s*per;
  int s1 = s0 + per; if (s1 > end) s1 = end;
  float acc = 0.f;
  for (int i = s0 + r; i < s1; i += 4)
    acc += v[(size_t)i*64 + d];
  red[r][d] = acc;
  __syncthreads();
  if (r == 0)
    partial[(size_t)blockIdx.x*64 + d] = red[0][d] + red[1][d] + red[2][d] + red[3][d];
}

// stage 2: B blocks; sum PS partials, mean, write emb twice + logits head.
__global__ void __launch_bounds__(64) k_head(
    const float* __restrict__ partial, const int* __restrict__ batch, int N, int B,
    const float* __restrict__ ldxb,
    const float* __restrict__ proj_w, const float* __restrict__ proj_b,
    const float* __restrict__ fc_w, const float* __restrict__ fc_b,
    float* __restrict__ out){
  __shared__ float ges[64];
  int b = blockIdx.x, d = threadIdx.x;
  int start = lower_bound_i(batch, N, b);
  int end   = lower_bound_i(batch, N, b + 1);
  float sum = 0.f;
#pragma unroll
  for (int s = 0; s < PS; ++s)
    sum += partial[((size_t)b*PS + s)*64 + d];
  float ge = sum / fmaxf((float)(end - start), 1.f);
  ges[d] = ge;
  out[(size_t)b*64 + d]                = ge;
  out[(size_t)B*64 + (size_t)b*64 + d] = ge;
  __syncthreads();
  if (d < 10){
    float acc = fc_b[d];
    float fl = ldxb[b];
    const float* fr = fc_w + d*164;
    for (int p = 0; p < 100; ++p) acc += (fl*proj_w[p] + proj_b[p]) * fr[p];
    for (int dd = 0; dd < 64; ++dd) acc += ges[dd]*fr[100 + dd];
    out[(size_t)B*128 + (size_t)b*10 + d] = acc;
  }
}

extern "C" void kernel_launch(void* const* d_in, const int* in_sizes, int n_in,
                              void* d_out, int out_size, void* d_ws, size_t ws_size,
                              hipStream_t stream){
  const float* x      = (const float*)d_in[0];
  const int*   ei     = (const int*)d_in[1];
  const float* ea     = (const float*)d_in[2];
  const int*   batch  = (const int*)d_in[3];
  const float* ldxb   = (const float*)d_in[4];
  const float* w_edge1= (const float*)d_in[5];
  const float* b_edge1= (const float*)d_in[6];
  const float* w_ih1  = (const float*)d_in[7];
  const float* w_hh1  = (const float*)d_in[8];
  const float* b_ih1  = (const float*)d_in[9];
  const float* b_hh1  = (const float*)d_in[10];
  const float* w_edge2= (const float*)d_in[11];
  const float* b_edge2= (const float*)d_in[12];
  const float* w_ih2  = (const float*)d_in[13];
  const float* w_hh2  = (const float*)d_in[14];
  const float* b_ih2  = (const float*)d_in[15];
  const float* b_hh2  = (const float*)d_in[16];
  const float* gate_w = (const float*)d_in[17];
  const float* gate_b = (const float*)d_in[18];
  const float* exp_w  = (const float*)d_in[19];
  const float* exp_b  = (const float*)d_in[20];
  const float* proj_w = (const float*)d_in[21];
  const float* proj_b = (const float*)d_in[22];
  const float* fc_w   = (const float*)d_in[23];
  const float* fc_b   = (const float*)d_in[24];
  float* out = (float*)d_out;

  int N = in_sizes[0] / 64;
  int E = in_sizes[1] / 2;
  int B = in_sizes[4];
  int tiles = (N + 15) / 16;
  int nTot = N * 64;

  // workspace layout (all segment sizes multiples of 16B)
  float*   m       = (float*)d_ws;                      // N*64 f32 (also MoE v)
  float*   h       = m + (size_t)nTot;                  // N*64 f32
  int4*    bkt     = (int4*)(h + (size_t)nTot);         // N*64 int4 {src,ea01,ea23,0}
  int*     cur     = (int*)(bkt + (size_t)nTot);        // 8*N i32   [sub*N+n]
  int*     ovfcnt  = cur + (size_t)N*8;                 // 4 i32 (padded)
  int*     ovf     = ovfcnt + 4;                        // OVF_MAX i32
  unsigned short* wbf = (unsigned short*)(ovf + OVF_MAX); // 65792 bf16
  float*   partial = (float*)(wbf + 65792);             // B*PS*64 f32
  unsigned short* x16 = (unsigned short*)(partial + (size_t)B*PS*64); // N*64 fp16
  unsigned short* h16 = x16 + (size_t)nTot;             // N*64 fp16
  unsigned short* wih1bf = wbf;
  unsigned short* whh1bf = wbf + 12288;
  unsigned short* wih2bf = wbf + 24576;
  unsigned short* whh2bf = wbf + 36864;
  unsigned short* gatebf = wbf + 49152;
  unsigned short* expbf  = wbf + 49408;

  dim3 blk(256);
  int edgeBlocks = (E + 511)/512;       // 2 edges per thread
  int nodeWaveBlocks = (N + 3)/4;       // one wave per node
  int N8 = N*8;
  int initThreads = N8 > 65792 ? N8 : 65792;
  if (nTot/8 > initThreads) initThreads = nTot/8;
  int initBlocks = (initThreads + 255)/256;

  k_init<<<initBlocks, blk, 0, stream>>>(w_ih1, w_hh1, w_ih2, w_hh2, gate_w, exp_w,
                                         wbf, cur, ovfcnt, N8, x, x16, nTot);
  k_bucket<<<edgeBlocks, blk, 0, stream>>>(ei, ea, cur, bkt, ovfcnt, ovf, E, N);
  // ---- layer 1 ----
  k_gather<<<nodeWaveBlocks, blk, 0, stream>>>(cur, bkt, x, x16, w_edge1, b_edge1, m, N);
  k_ovf<<<8, blk, 0, stream>>>(ei, ea, x, w_edge1, ovf, ovfcnt, m, E);
  k_gru<<<tiles, blk, 0, stream>>>(m, x, wih1bf, whh1bf, b_ih1, b_hh1, h, h16, tiles, N);
  // ---- layer 2 (in-place h update; barrier after fragment loads, safe) ----
  k_gather<<<nodeWaveBlocks, blk, 0, stream>>>(cur, bkt, h, h16, w_edge2, b_edge2, m, N);
  k_ovf<<<8, blk, 0, stream>>>(ei, ea, h, w_edge2, ovf, ovfcnt, m, E);
  k_gru<<<tiles, blk, 0, stream>>>(m, h, wih2bf, whh2bf, b_ih2, b_hh2, h, (unsigned short*)nullptr, tiles, N);
  // ---- MoE -> v (reuse m), two-stage segmented-mean pool + heads ----
  k_moe<<<tiles, blk, 0, stream>>>(h, gatebf, gate_b, expbf, exp_b, m, tiles, N);
  k_pool<<<B*PS, blk, 0, stream>>>(m, batch, N, partial);
  k_head<<<B, 64, 0, stream>>>(partial, batch, N, B, ldxb, proj_w, proj_b, fc_w, fc_b, out);
}